// Round 9
// baseline (228.746 us; speedup 1.0000x reference)
//
#include <hip/hip_runtime.h>
#include <hip/hip_bf16.h>
#include <math.h>

#define BQ 100
#define SB 8
#define SS 4096
#define DD 256
#define HH 8
#define HDD 32
#define NSPLIT 4
#define SCHUNK (SS / NSPLIT)   // 1024
#define MROWS 800              // SB*BQ

typedef __attribute__((ext_vector_type(8))) short bf16x8;
typedef __attribute__((ext_vector_type(4))) float f32x4;

__device__ inline unsigned short f2bf(float f) {
    union { float f; unsigned u; } v; v.f = f;
    unsigned r = v.u + 0x7fff + ((v.u >> 16) & 1);
    return (unsigned short)(r >> 16);
}

// HW packed fp32x2 -> bf16x2 (v_cvt_pk_bf16_f32 on gfx950), RNE
__device__ inline unsigned pkbf(float x, float y) {
    union { __hip_bfloat162 h; unsigned u; } c;
    c.h = __float22bfloat162_rn(make_float2(x, y));
    return c.u;
}

// async global->LDS, 16B per lane.
typedef __attribute__((address_space(1))) const void gas_void;
typedef __attribute__((address_space(3))) void las_void;
__device__ inline void gl_lds16(const unsigned short* g, unsigned short* l) {
    __builtin_amdgcn_global_load_lds((gas_void*)g, (las_void*)l, 16, 0, 0);
}

#define TM 128
#define TN 128
#define QSCALE 0.17677669529663687f

// bf16 weight workspace offsets (in shorts)
#define WOFF_CW   0          // cross_in_w  768x256
#define WOFF_SIW  196608     // self_in_w   768x256
#define WOFF_COW  393216     // cross_out_w 256x256
#define WOFF_SOW  458752     // self_out_w  256x256
#define WOFF_F1   524288     // ffn_w1     1024x256
#define WOFF_F2   786432     // ffn_w2      256x1024
#define WTOT      1048576

// ============ wprep: weights + pixel_feat -> bf16 (once / iter) ============
__global__ __launch_bounds__(256) void wprep(
        const float* __restrict__ cw, const float* __restrict__ siw,
        const float* __restrict__ cow, const float* __restrict__ sow,
        const float* __restrict__ f1, const float* __restrict__ f2,
        const float* __restrict__ pix,
        unsigned short* __restrict__ o, unsigned short* __restrict__ abf) {
    int b = blockIdx.x;
    int t = threadIdx.x;
    if (b >= 512) {
        size_t off = (size_t)(b - 512) * 2048 + (size_t)t * 8;
        const float* p = pix + off;
        float4 a = *(const float4*)p;
        float4 c = *(const float4*)(p + 4);
        uint4 pk;
        pk.x = pkbf(a.x, a.y); pk.y = pkbf(a.z, a.w);
        pk.z = pkbf(c.x, c.y); pk.w = pkbf(c.z, c.w);
        *(uint4*)(abf + off) = pk;
        return;
    }
    const float* src; size_t so, doff;
    if (b < 96)       { src = cw;  so = (size_t)b * 2048;         doff = WOFF_CW; }
    else if (b < 192) { src = siw; so = (size_t)(b - 96) * 2048;  doff = WOFF_SIW; }
    else if (b < 224) { src = cow; so = (size_t)(b - 192) * 2048; doff = WOFF_COW; }
    else if (b < 256) { src = sow; so = (size_t)(b - 224) * 2048; doff = WOFF_SOW; }
    else if (b < 384) { src = f1;  so = (size_t)(b - 256) * 2048; doff = WOFF_F1; }
    else              { src = f2;  so = (size_t)(b - 384) * 2048; doff = WOFF_F2; }
    const float* p = src + so + (size_t)t * 8;
    float4 a = *(const float4*)p;
    float4 c = *(const float4*)(p + 4);
    uint4 pk;
    pk.x = pkbf(a.x, a.y); pk.y = pkbf(a.z, a.w);
    pk.z = pkbf(c.x, c.y); pk.w = pkbf(c.z, c.w);
    *(uint4*)(o + doff + so + (size_t)t * 8) = pk;
}

// ============ stage1: fused {KV projection | maskpack | LN+Q-projection} ====
// q_cross bf16 PRE-SCALED by 1/sqrt(HD).
__global__ __launch_bounds__(256, 3) void stage1(
        const float* __restrict__ queries,
        const float* __restrict__ ln_g, const float* __restrict__ ln_b,
        const unsigned short* __restrict__ wbf,
        const float* __restrict__ cb,
        unsigned short* __restrict__ q_cross,
        const unsigned short* __restrict__ Abf,
        unsigned short* __restrict__ Kb, unsigned short* __restrict__ Vb,
        const float* __restrict__ mask, unsigned* __restrict__ Mbits) {
    __shared__ __align__(16) char smem[32768];
    const int bid = blockIdx.x;
    const int t = threadIdx.x;

    if (bid < 1024) {
        unsigned short* Sbuf = (unsigned short*)smem;  // 2 x (A 4096 + B 4096)
        const unsigned short* Wb = wbf + (size_t)DD * DD;
        const float* bias = cb + DD;
        int xcd = bid & 7, idx = bid >> 3;
        int mtile = xcd + 8 * (idx >> 2);
        int ntl = idx & 3;
        int m0 = mtile * TM, n0 = ntl * TN;
        int wave = t >> 6, lane = t & 63;
        int wm = (wave & 1) * 64, wn = (wave >> 1) * 64;
        int fr = lane & 15, quad = lane >> 4;
        f32x4 acc[4][4] = {};

        const int c0 = t, c1 = 256 + t;
        const int r0 = c0 >> 2, r1 = c1 >> 2;
        const int cc0 = (c0 & 3) ^ ((r0 >> 1) & 3);
        const int cc1 = (c1 & 3) ^ ((r1 >> 1) & 3);

        gl_lds16(Abf + (size_t)(m0 + r0) * DD + cc0 * 8, Sbuf + c0 * 8);
        gl_lds16(Abf + (size_t)(m0 + r1) * DD + cc1 * 8, Sbuf + c1 * 8);
        gl_lds16(Wb + (size_t)(n0 + r0) * DD + cc0 * 8, Sbuf + 4096 + c0 * 8);
        gl_lds16(Wb + (size_t)(n0 + r1) * DD + cc1 * 8, Sbuf + 4096 + c1 * 8);
        __syncthreads();

#pragma unroll
        for (int ks = 0; ks < 8; ks++) {
            unsigned short* Ab = Sbuf + (ks & 1) * 8192;
            unsigned short* Bb = Ab + 4096;
            if (ks < 7) {
                unsigned short* An = Sbuf + ((ks + 1) & 1) * 8192;
                unsigned short* Bn = An + 4096;
                int k0 = (ks + 1) * 32;
                gl_lds16(Abf + (size_t)(m0 + r0) * DD + k0 + cc0 * 8, An + c0 * 8);
                gl_lds16(Abf + (size_t)(m0 + r1) * DD + k0 + cc1 * 8, An + c1 * 8);
                gl_lds16(Wb + (size_t)(n0 + r0) * DD + k0 + cc0 * 8, Bn + c0 * 8);
                gl_lds16(Wb + (size_t)(n0 + r1) * DD + k0 + cc1 * 8, Bn + c1 * 8);
            }
            bf16x8 af[4], bv[4];
#pragma unroll
            for (int mi = 0; mi < 4; mi++) {
                int row = wm + mi * 16 + fr;
                int j = quad ^ ((row >> 1) & 3);
                af[mi] = *(const bf16x8*)(Ab + row * 32 + j * 8);
            }
#pragma unroll
            for (int ni = 0; ni < 4; ni++) {
                int row = wn + ni * 16 + fr;
                int j = quad ^ ((row >> 1) & 3);
                bv[ni] = *(const bf16x8*)(Bb + row * 32 + j * 8);
            }
#pragma unroll
            for (int mi = 0; mi < 4; mi++) {
                acc[mi][0] = __builtin_amdgcn_mfma_f32_16x16x32_bf16(af[mi], bv[0], acc[mi][0], 0, 0, 0);
                acc[mi][1] = __builtin_amdgcn_mfma_f32_16x16x32_bf16(af[mi], bv[1], acc[mi][1], 0, 0, 0);
                acc[mi][2] = __builtin_amdgcn_mfma_f32_16x16x32_bf16(af[mi], bv[2], acc[mi][2], 0, 0, 0);
                acc[mi][3] = __builtin_amdgcn_mfma_f32_16x16x32_bf16(af[mi], bv[3], acc[mi][3], 0, 0, 0);
            }
            __syncthreads();
        }
#pragma unroll
        for (int ni = 0; ni < 4; ni++) {
            int n = n0 + wn + ni * 16 + fr;
            float bv = bias[n];
            int hh = (n >> 5) & 7, d = n & 31;
            if (n < 256) {                         // K: [b,h,s,d]
#pragma unroll
                for (int mi = 0; mi < 4; mi++) {
#pragma unroll
                    for (int r = 0; r < 4; r++) {
                        int m = m0 + wm + mi * 16 + quad * 4 + r;
                        int bb = m >> 12, s = m & (SS - 1);
                        Kb[((((size_t)bb * HH + hh) * SS + s) << 5) + d] =
                            f2bf(acc[mi][ni][r] + bv);
                    }
                }
            } else {                               // V: [b,h,d,s], 8B stores
#pragma unroll
                for (int mi = 0; mi < 4; mi++) {
                    int m = m0 + wm + mi * 16 + quad * 4;
                    int bb = m >> 12, s = m & (SS - 1);
                    union { unsigned short u[4]; uint2 v; } pk;
#pragma unroll
                    for (int r = 0; r < 4; r++)
                        pk.u[r] = f2bf(acc[mi][ni][r] + bv);
                    *(uint2*)&Vb[(((size_t)bb * HH + hh) * 32 + d) * SS + s] = pk.v;
                }
            }
        }
    } else if (bid < 1824) {
        int row = bid - 1024;
        unsigned* words = (unsigned*)smem;
        unsigned* orred = (unsigned*)(smem + 512);
        int w = t >> 6, lane = t & 63;
        const float* mp = mask + (size_t)row * SS + lane;
        float mv[16];
#pragma unroll
        for (int i = 0; i < 16; i++) mv[i] = mp[(w * 16 + i) * 64];
        unsigned lor = 0;
#pragma unroll
        for (int i = 0; i < 16; i++) {
            unsigned long long bal = __ballot(mv[i] > 0.f);
            if (lane == 0) {
                words[(w * 16 + i) * 2] = (unsigned)bal;
                words[(w * 16 + i) * 2 + 1] = (unsigned)(bal >> 32);
            }
            lor |= (unsigned)(bal | (bal >> 32));
        }
        if (lane == 0) orred[w] = lor;
        __syncthreads();
        unsigned anyv = orred[0] | orred[1] | orred[2] | orred[3];
        if (t < 128) Mbits[(size_t)row * 128 + t] = anyv ? words[t] : 0xFFFFFFFFu;
    } else {
        typedef unsigned short (*arow_t)[264];
        arow_t Aq = (arow_t)smem;
        float* mu_s = (float*)(smem + 16896);
        float* rs_s = mu_s + 32;
        float (*prt)[8][2] = (float(*)[8][2])(rs_s + 32);
        int idx = bid - 1824;
        int nq = idx & 1, my = idx >> 1;
        int m0 = my * 32;
        int row = t & 31, cs = t >> 5;
        const float* xp = queries + (size_t)(m0 + row) * DD + cs * 32;
        float s = 0.f, ss = 0.f;
#pragma unroll
        for (int c = 0; c < 32; c += 4) {
            float4 v = *(const float4*)(xp + c);
            s += v.x + v.y + v.z + v.w;
            ss += v.x * v.x + v.y * v.y + v.z * v.z + v.w * v.w;
        }
        prt[row][cs][0] = s; prt[row][cs][1] = ss;
        __syncthreads();
        if (t < 32) {
            float sum = 0.f, sq = 0.f;
#pragma unroll
            for (int k = 0; k < 8; k++) { sum += prt[t][k][0]; sq += prt[t][k][1]; }
            float mu = sum * (1.0f / DD);
            float var = sq * (1.0f / DD) - mu * mu;
            mu_s[t] = mu;
            rs_s[t] = rsqrtf(var + 1e-5f);
        }
        __syncthreads();
        {
            float mu = mu_s[row], r = rs_s[row];
            int col0 = cs * 32;
#pragma unroll
            for (int c = 0; c < 32; c += 8) {
                int col = col0 + c;
                float4 v0 = *(const float4*)(xp + c);
                float4 v1 = *(const float4*)(xp + c + 4);
                float4 g0 = *(const float4*)(ln_g + col);
                float4 g1 = *(const float4*)(ln_g + col + 4);
                float4 b0 = *(const float4*)(ln_b + col);
                float4 b1 = *(const float4*)(ln_b + col + 4);
                uint4 pk;
                pk.x = pkbf((v0.x - mu) * r * g0.x + b0.x, (v0.y - mu) * r * g0.y + b0.y);
                pk.y = pkbf((v0.z - mu) * r * g0.z + b0.z, (v0.w - mu) * r * g0.w + b0.w);
                pk.z = pkbf((v1.x - mu) * r * g1.x + b1.x, (v1.y - mu) * r * g1.y + b1.y);
                pk.w = pkbf((v1.z - mu) * r * g1.z + b1.z, (v1.w - mu) * r * g1.w + b1.w);
                *(uint4*)&Aq[row][col] = pk;
            }
        }
        __syncthreads();
        int w = t >> 6, lane = t & 63;
        int fr = lane & 15, quad = lane >> 4;
        int n0 = nq * 128 + w * 32;
        f32x4 acc[2][2] = {};
        const unsigned short* Wq0 = wbf + (size_t)(n0 + fr) * DD + quad * 8;
        const unsigned short* Wq1 = Wq0 + (size_t)16 * DD;
#pragma unroll
        for (int k0 = 0; k0 < DD; k0 += 32) {
            bf16x8 a0 = *(const bf16x8*)&Aq[fr][k0 + quad * 8];
            bf16x8 a1 = *(const bf16x8*)&Aq[16 + fr][k0 + quad * 8];
            bf16x8 w0 = *(const bf16x8*)(Wq0 + k0);
            bf16x8 w1 = *(const bf16x8*)(Wq1 + k0);
            acc[0][0] = __builtin_amdgcn_mfma_f32_16x16x32_bf16(a0, w0, acc[0][0], 0, 0, 0);
            acc[0][1] = __builtin_amdgcn_mfma_f32_16x16x32_bf16(a0, w1, acc[0][1], 0, 0, 0);
            acc[1][0] = __builtin_amdgcn_mfma_f32_16x16x32_bf16(a1, w0, acc[1][0], 0, 0, 0);
            acc[1][1] = __builtin_amdgcn_mfma_f32_16x16x32_bf16(a1, w1, acc[1][1], 0, 0, 0);
        }
#pragma unroll
        for (int ni = 0; ni < 2; ni++) {
            int n = n0 + ni * 16 + fr;
            float bv = cb[n];
#pragma unroll
            for (int mi = 0; mi < 2; mi++) {
#pragma unroll
                for (int r = 0; r < 4; r++) {
                    int m = m0 + mi * 16 + quad * 4 + r;
                    q_cross[(size_t)m * DD + n] =
                        f2bf((acc[mi][ni][r] + bv) * QSCALE);
                }
            }
        }
    }
}

// ---------------- fused LayerNorm + one-wave MFMA GEMM ----------------------
template<int MODE>
__global__ __launch_bounds__(64, 4) void ln_gemm(
        const float* __restrict__ X, const float* __restrict__ gam,
        const float* __restrict__ bet,
        const unsigned short* __restrict__ W, const float* __restrict__ bias,
        const float* __restrict__ res,
        float* __restrict__ C, unsigned short* __restrict__ Cb, int N) {
    __shared__ unsigned short As[32][264];
    __shared__ float mu_s[32], rs_s[32];
    __shared__ float prt[32][2][2];
    const int t = threadIdx.x;
    const int fr = t & 15, quad = t >> 4;
    const int m0 = blockIdx.y * 32, n0 = blockIdx.x * 32;
    const int row = t & 31, half = t >> 5;

    const float* xp = X + (size_t)(m0 + row) * DD + half * 128;
    float s = 0.f, ss = 0.f;
#pragma unroll
    for (int c = 0; c < 128; c += 4) {
        float4 v = *(const float4*)(xp + c);
        s += v.x + v.y + v.z + v.w;
        ss += v.x * v.x + v.y * v.y + v.z * v.z + v.w * v.w;
    }
    prt[row][half][0] = s;
    prt[row][half][1] = ss;
    __syncthreads();
    if (t < 32) {
        float sum = prt[t][0][0] + prt[t][1][0];
        float sq  = prt[t][0][1] + prt[t][1][1];
        float mu = sum * (1.0f / DD);
        float var = sq * (1.0f / DD) - mu * mu;
        mu_s[t] = mu;
        rs_s[t] = rsqrtf(var + 1e-5f);
    }
    __syncthreads();
    {
        float mu = mu_s[row], r = rs_s[row];
#pragma unroll
        for (int c = 0; c < 128; c += 8) {
            int col = half * 128 + c;
            float4 v0 = *(const float4*)(xp + c);
            float4 v1 = *(const float4*)(xp + c + 4);
            float4 g0 = *(const float4*)(gam + col);
            float4 g1 = *(const float4*)(gam + col + 4);
            float4 b0 = *(const float4*)(bet + col);
            float4 b1 = *(const float4*)(bet + col + 4);
            uint4 pk;
            pk.x = pkbf((v0.x - mu) * r * g0.x + b0.x, (v0.y - mu) * r * g0.y + b0.y);
            pk.y = pkbf((v0.z - mu) * r * g0.z + b0.z, (v0.w - mu) * r * g0.w + b0.w);
            pk.z = pkbf((v1.x - mu) * r * g1.x + b1.x, (v1.y - mu) * r * g1.y + b1.y);
            pk.w = pkbf((v1.z - mu) * r * g1.z + b1.z, (v1.w - mu) * r * g1.w + b1.w);
            *(uint4*)&As[row][col] = pk;
        }
    }
    __syncthreads();

    f32x4 acc[2][2] = {};
    const unsigned short* Wp0 = W + (size_t)(n0 + fr) * DD + quad * 8;
    const unsigned short* Wp1 = Wp0 + (size_t)16 * DD;
#pragma unroll
    for (int k0 = 0; k0 < DD; k0 += 32) {
        bf16x8 a0 = *(const bf16x8*)&As[fr][k0 + quad * 8];
        bf16x8 a1 = *(const bf16x8*)&As[16 + fr][k0 + quad * 8];
        bf16x8 w0 = *(const bf16x8*)(Wp0 + k0);
        bf16x8 w1 = *(const bf16x8*)(Wp1 + k0);
        acc[0][0] = __builtin_amdgcn_mfma_f32_16x16x32_bf16(a0, w0, acc[0][0], 0, 0, 0);
        acc[0][1] = __builtin_amdgcn_mfma_f32_16x16x32_bf16(a0, w1, acc[0][1], 0, 0, 0);
        acc[1][0] = __builtin_amdgcn_mfma_f32_16x16x32_bf16(a1, w0, acc[1][0], 0, 0, 0);
        acc[1][1] = __builtin_amdgcn_mfma_f32_16x16x32_bf16(a1, w1, acc[1][1], 0, 0, 0);
    }

#pragma unroll
    for (int ni = 0; ni < 2; ni++) {
        int n = n0 + ni * 16 + fr;
        float bv = bias[n];
#pragma unroll
        for (int mi = 0; mi < 2; mi++) {
#pragma unroll
            for (int r = 0; r < 4; r++) {
                int m = m0 + mi * 16 + quad * 4 + r;
                float v = acc[mi][ni][r] + bv;
                if (MODE == 1) {
                    v = 0.5f * v * (1.0f + erff(v * 0.70710678118654752f));
                    Cb[(size_t)m * N + n] = f2bf(v);
                } else if (MODE == 2) {
                    v += res[(size_t)m * N + n];
                    C[(size_t)m * N + n] = v;
                } else if (MODE == 3) {
                    if (n < 256) v *= QSCALE;
                    Cb[(size_t)m * N + n] = f2bf(v);
                } else {
                    C[(size_t)m * N + n] = v;
                }
            }
        }
    }
}

// ---------------- fused split-S combine + output projection -----------------
__global__ __launch_bounds__(64, 4) void comb_gemm(
        const float* __restrict__ Opart, const float* __restrict__ mpart,
        const float* __restrict__ lpart,
        const unsigned short* __restrict__ W, const float* __restrict__ bias,
        const float* __restrict__ res,
        float* __restrict__ C) {
    __shared__ unsigned short As[32][264];
    const int t = threadIdx.x;
    const int fr = t & 15, quad = t >> 4;
    const int m0 = blockIdx.y * 32, n0 = blockIdx.x * 32;
    const int row = t & 31, half = t >> 5;

    {
        int m = m0 + row;
        int b = m / BQ, q = m % BQ;
#pragma unroll
        for (int h = half * 4; h < half * 4 + 4; h++) {
            float mv[NSPLIT], wsp[NSPLIT];
            float mstar = -1e30f;
#pragma unroll
            for (int sp = 0; sp < NSPLIT; sp++) {
                mv[sp] = mpart[((size_t)(b * NSPLIT + sp) * HH + h) * BQ + q];
                mstar = fmaxf(mstar, mv[sp]);
            }
            float lstar = 0.f;
#pragma unroll
            for (int sp = 0; sp < NSPLIT; sp++) {
                wsp[sp] = __expf(mv[sp] - mstar);
                lstar += lpart[((size_t)(b * NSPLIT + sp) * HH + h) * BQ + q] * wsp[sp];
            }
            float inv = 1.0f / lstar;
#pragma unroll
            for (int d = 0; d < HDD; d += 8) {
                float o[8] = {};
#pragma unroll
                for (int sp = 0; sp < NSPLIT; sp++) {
                    const float* op = Opart +
                        ((size_t)(b * NSPLIT + sp) * BQ + q) * DD + h * HDD + d;
                    float4 a = *(const float4*)op;
                    float4 b4 = *(const float4*)(op + 4);
                    o[0] += a.x * wsp[sp];  o[1] += a.y * wsp[sp];
                    o[2] += a.z * wsp[sp];  o[3] += a.w * wsp[sp];
                    o[4] += b4.x * wsp[sp]; o[5] += b4.y * wsp[sp];
                    o[6] += b4.z * wsp[sp]; o[7] += b4.w * wsp[sp];
                }
                uint4 pk;
                pk.x = pkbf(o[0] * inv, o[1] * inv);
                pk.y = pkbf(o[2] * inv, o[3] * inv);
                pk.z = pkbf(o[4] * inv, o[5] * inv);
                pk.w = pkbf(o[6] * inv, o[7] * inv);
                *(uint4*)&As[row][h * HDD + d] = pk;
            }
        }
    }
    __syncthreads();

    f32x4 acc[2][2] = {};
    const unsigned short* Wp0 = W + (size_t)(n0 + fr) * DD + quad * 8;
    const unsigned short* Wp1 = Wp0 + (size_t)16 * DD;
#pragma unroll
    for (int k0 = 0; k0 < DD; k0 += 32) {
        bf16x8 a0 = *(const bf16x8*)&As[fr][k0 + quad * 8];
        bf16x8 a1 = *(const bf16x8*)&As[16 + fr][k0 + quad * 8];
        bf16x8 w0 = *(const bf16x8*)(Wp0 + k0);
        bf16x8 w1 = *(const bf16x8*)(Wp1 + k0);
        acc[0][0] = __builtin_amdgcn_mfma_f32_16x16x32_bf16(a0, w0, acc[0][0], 0, 0, 0);
        acc[0][1] = __builtin_amdgcn_mfma_f32_16x16x32_bf16(a0, w1, acc[0][1], 0, 0, 0);
        acc[1][0] = __builtin_amdgcn_mfma_f32_16x16x32_bf16(a1, w0, acc[1][0], 0, 0, 0);
        acc[1][1] = __builtin_amdgcn_mfma_f32_16x16x32_bf16(a1, w1, acc[1][1], 0, 0, 0);
    }

#pragma unroll
    for (int ni = 0; ni < 2; ni++) {
        int n = n0 + ni * 16 + fr;
        float bv = bias[n];
#pragma unroll
        for (int mi = 0; mi < 2; mi++) {
#pragma unroll
            for (int r = 0; r < 4; r++) {
                int m = m0 + mi * 16 + quad * 4 + r;
                float v = acc[mi][ni][r] + bv + res[(size_t)m * DD + n];
                C[(size_t)m * DD + n] = v;
            }
        }
    }
}

// ---------------- one-wave MFMA GEMM: bf16 A, 32x32 tile, optional split-K --
template<int KK, int SPLITK, int MODE>
__global__ __launch_bounds__(64, 4) void gemm_skinny2(
        const unsigned short* __restrict__ A, const unsigned short* __restrict__ W,
        const float* __restrict__ bias, const float* __restrict__ res,
        float* __restrict__ C, float* __restrict__ Cp, int N) {
    const int lane = threadIdx.x;
    const int fr = lane & 15, quad = lane >> 4;
    const int m0 = blockIdx.y * 32;
    const int n0 = blockIdx.x * 32;
    const int sk = blockIdx.z;
    const int KCH = KK / SPLITK;

    f32x4 acc[2][2] = {};
    const unsigned short* Ap0 = A + (size_t)(m0 + fr) * KK + sk * KCH + quad * 8;
    const unsigned short* Ap1 = Ap0 + (size_t)16 * KK;
    const unsigned short* Wp0 = W + (size_t)(n0 + fr) * KK + sk * KCH + quad * 8;
    const unsigned short* Wp1 = Wp0 + (size_t)16 * KK;

#pragma unroll
    for (int k0 = 0; k0 < KCH; k0 += 32) {
        bf16x8 a0 = *(const bf16x8*)(Ap0 + k0);
        bf16x8 a1 = *(const bf16x8*)(Ap1 + k0);
        bf16x8 w0 = *(const bf16x8*)(Wp0 + k0);
        bf16x8 w1 = *(const bf16x8*)(Wp1 + k0);
        acc[0][0] = __builtin_amdgcn_mfma_f32_16x16x32_bf16(a0, w0, acc[0][0], 0, 0, 0);
        acc[0][1] = __builtin_amdgcn_mfma_f32_16x16x32_bf16(a0, w1, acc[0][1], 0, 0, 0);
        acc[1][0] = __builtin_amdgcn_mfma_f32_16x16x32_bf16(a1, w0, acc[1][0], 0, 0, 0);
        acc[1][1] = __builtin_amdgcn_mfma_f32_16x16x32_bf16(a1, w1, acc[1][1], 0, 0, 0);
    }

    if (SPLITK == 1) {
#pragma unroll
        for (int ni = 0; ni < 2; ni++) {
            int n = n0 + ni * 16 + fr;
            float bv = bias[n];
#pragma unroll
            for (int mi = 0; mi < 2; mi++) {
#pragma unroll
                for (int r = 0; r < 4; r++) {
                    int m = m0 + mi * 16 + quad * 4 + r;
                    float v = acc[mi][ni][r] + bv;
                    if (MODE == 1) {
                        v = 0.5f * v * (1.0f + erff(v * 0.70710678118654752f));
                    } else if (MODE == 2) {
                        v += res[(size_t)m * N + n];
                    }
                    C[(size_t)m * N + n] = v;
                }
            }
        }
    } else {
        float* dst = Cp + (size_t)sk * MROWS * N;
#pragma unroll
        for (int ni = 0; ni < 2; ni++) {
            int n = n0 + ni * 16 + fr;
#pragma unroll
            for (int mi = 0; mi < 2; mi++) {
#pragma unroll
                for (int r = 0; r < 4; r++) {
                    int m = m0 + mi * 16 + quad * 4 + r;
                    dst[(size_t)m * N + n] = acc[mi][ni][r];
                }
            }
        }
    }
}

// ---------------- split-K combine: sum partials + epilogue ------------------
template<int SPLITK, int MODE>
__global__ void gemm_combine(const float* __restrict__ Cp,
                             const float* __restrict__ bias,
                             const float* __restrict__ res,
                             float* __restrict__ C, int N) {
    int m = blockIdx.x;
    for (int n = threadIdx.x; n < N; n += 256) {
        float v = bias[n];
#pragma unroll
        for (int sk = 0; sk < SPLITK; sk++)
            v += Cp[((size_t)sk * MROWS + m) * N + n];
        if (MODE == 1) {
            v = 0.5f * v * (1.0f + erff(v * 0.70710678118654752f));
        } else if (MODE == 2) {
            v += res[(size_t)m * N + n];
        }
        C[(size_t)m * N + n] = v;
    }
}

// ---------------- MFMA flash cross-attention, split-S, 64-q tiles -----------
// K and Mbits read DIRECT per-lane from global (no reuse -> no LDS staging);
// V (4x cross-wave reuse) staged in LDS via reg-prefetch (T14): next tile's
// loads issued right after this tile's ds_write, hiding HBM latency under
// QK^T + softmax. 3 barriers per S-tile.
#define QT 64
#define ST 128

__global__ __launch_bounds__(256) void cross_attn_mfma(
        const unsigned short* __restrict__ Qm,
        const unsigned short* __restrict__ Kb,
        const unsigned short* __restrict__ Vb,
        const unsigned* __restrict__ Mbits,
        float* __restrict__ Opart,
        float* __restrict__ mpart,
        float* __restrict__ lpart) {
    __shared__ unsigned short Qs[QT][40];
    __shared__ unsigned short Vt[HDD][136];
    __shared__ unsigned short Ps[QT][136];
    __shared__ float4 redm[QT];
    __shared__ float4 reds[QT];
    __shared__ float m_s[QT], alpha_s[QT], l_s[QT];

    const int qb = blockIdx.x, h = blockIdx.y;
    const int b = blockIdx.z / NSPLIT, sp = blockIdx.z % NSPLIT;
    const int t = threadIdx.x;
    const int w = t >> 6, lane = t & 63;
    const int fr = lane & 15, quad = lane >> 4;
    const int q0 = qb * QT;
    const int qlim = min(BQ - q0, QT);

    {
        int q = t >> 2, c0 = (t & 3) * 8;
        uint4 pq = {0, 0, 0, 0};
        if (q < qlim)
            pq = *(const uint4*)(Qm + (size_t)(b * BQ + q0 + q) * DD + h * HDD + c0);
        *(uint4*)&Qs[q][c0] = pq;
        if (t < QT) { m_s[t] = -1e30f; l_s[t] = 0.f; }
    }

    f32x4 oacc[2] = {};
    const unsigned short* Kbase = Kb + (((size_t)(b * HH + h)) * SS << 5);
    const unsigned short* Vbase = Vb + (((size_t)(b * HH + h)) << 5) * SS;
    const int vd = t >> 3, vc = (t & 7) * 16;
    const unsigned short* vrow = Vbase + (size_t)vd * SS;

    const int send = (sp + 1) * SCHUNK;
    // prologue: V tile 0 into regs
    uint4 vr0 = *(const uint4*)(vrow + sp * SCHUNK + vc);
    uint4 vr1 = *(const uint4*)(vrow + sp * SCHUNK + vc + 8);

    for (int s0 = sp * SCHUNK; s0 < send; s0 += ST) {
        // direct K loads (per-lane A-operand rows) + direct Mbits loads;
        // issued before B1 so latency overlaps barrier wait.
        bf16x8 af[2];
#pragma unroll
        for (int mt = 0; mt < 2; mt++)
            af[mt] = *(const bf16x8*)(Kbase +
                ((size_t)(s0 + w * 32 + mt * 16 + fr) << 5) + quad * 8);
        unsigned mw[4];
#pragma unroll
        for (int nt = 0; nt < 4; nt++) {
            int q = nt * 16 + fr;
            mw[nt] = (q < qlim)
                ? Mbits[(size_t)(b * BQ + q0 + q) * 128 + (s0 >> 5) + w]
                : 0xFFFFFFFFu;
        }
        __syncthreads();                               // B1: prev PV done
        // stage V (regs -> LDS), then prefetch next tile into regs
        *(uint4*)&Vt[vd][vc] = vr0;
        *(uint4*)&Vt[vd][vc + 8] = vr1;
        if (s0 + ST < send) {
            vr0 = *(const uint4*)(vrow + s0 + ST + vc);
            vr1 = *(const uint4*)(vrow + s0 + ST + vc + 8);
        }

        float mo[4];
#pragma unroll
        for (int nt = 0; nt < 4; nt++) mo[nt] = m_s[nt * 16 + fr];

        f32x4 st[2][4];
#pragma unroll
        for (int nt = 0; nt < 4; nt++) {
            bf16x8 bq = *(const bf16x8*)&Qs[nt * 16 + fr][quad * 8];
#pragma unroll
            for (int mt = 0; mt < 2; mt++) {
                f32x4 z = {0.f, 0.f, 0.f, 0.f};
                st[mt][nt] = __builtin_amdgcn_mfma_f32_16x16x32_bf16(af[mt], bq, z, 0, 0, 0);
            }
        }

        float pmax[4];
#pragma unroll
        for (int nt = 0; nt < 4; nt++) {
            pmax[nt] = -1e30f;
#pragma unroll
            for (int mt = 0; mt < 2; mt++)
#pragma unroll
                for (int r = 0; r < 4; r++) {
                    int bitpos = mt * 16 + quad * 4 + r;
                    float v = st[mt][nt][r];
                    if (!((mw[nt] >> bitpos) & 1u)) v -= 10000.f;
                    st[mt][nt][r] = v;
                    pmax[nt] = fmaxf(pmax[nt], v);
                }
        }
#pragma unroll
        for (int nt = 0; nt < 4; nt++) {
            pmax[nt] = fmaxf(pmax[nt], __shfl_xor(pmax[nt], 16));
            pmax[nt] = fmaxf(pmax[nt], __shfl_xor(pmax[nt], 32));
        }
        if (quad == 0) {
#pragma unroll
            for (int nt = 0; nt < 4; nt++)
                ((float*)&redm[nt * 16 + fr])[w] = pmax[nt];
        }
        __syncthreads();                               // B3: redm visible

        float mn[4], al[4];
#pragma unroll
        for (int nt = 0; nt < 4; nt++) {
            float4 rr = redm[nt * 16 + fr];
            float mt4 = fmaxf(fmaxf(rr.x, rr.y), fmaxf(rr.z, rr.w));
            mn[nt] = fmaxf(mo[nt], mt4);
            al[nt] = __expf(mo[nt] - mn[nt]);
        }
        if (w == 0 && quad == 0) {
#pragma unroll
            for (int nt = 0; nt < 4; nt++) {
                m_s[nt * 16 + fr] = mn[nt];
                alpha_s[nt * 16 + fr] = al[nt];
            }
        }

        float psum[4];
#pragma unroll
        for (int nt = 0; nt < 4; nt++) {
            psum[nt] = 0.f;
#pragma unroll
            for (int mt = 0; mt < 2; mt++) {
                float p0 = __expf(st[mt][nt][0] - mn[nt]);
                float p1 = __expf(st[mt][nt][1] - mn[nt]);
                float p2 = __expf(st[mt][nt][2] - mn[nt]);
                float p3 = __expf(st[mt][nt][3] - mn[nt]);
                psum[nt] += p0 + p1 + p2 + p3;
                uint2 pk;
                pk.x = pkbf(p0, p1);
                pk.y = pkbf(p2, p3);
                *(uint2*)&Ps[nt * 16 + fr][w * 32 + mt * 16 + quad * 4] = pk;
            }
        }
#pragma unroll
        for (int nt = 0; nt < 4; nt++) {
            psum[nt] += __shfl_xor(psum[nt], 16);
            psum[nt] += __shfl_xor(psum[nt], 32);
        }
        if (quad == 0) {
#pragma unroll
            for (int nt = 0; nt < 4; nt++)
                ((float*)&reds[nt * 16 + fr])[w] = psum[nt];
        }
        __syncthreads();                               // B4: Ps/Vt/alpha/reds

        if (w == 0 && quad == 0) {
#pragma unroll
            for (int nt = 0; nt < 4; nt++) {
                int q = nt * 16 + fr;
                float4 ssum = reds[q];
                l_s[q] = l_s[q] * al[nt] + (ssum.x + ssum.y + ssum.z + ssum.w);
            }
        }

#pragma unroll
        for (int r = 0; r < 4; r++) {
            float a = alpha_s[w * 16 + quad * 4 + r];
            oacc[0][r] *= a; oacc[1][r] *= a;
        }
#pragma unroll
        for (int k0 = 0; k0 < ST; k0 += 32) {
            bf16x8 ap = *(const bf16x8*)&Ps[w * 16 + fr][k0 + quad * 8];
            bf16x8 bv0 = *(const bf16x8*)&Vt[fr][k0 + quad * 8];
            bf16x8 bv1 = *(const bf16x8*)&Vt[16 + fr][k0 + quad * 8];
            oacc[0] = __builtin_amdgcn_mfma_f32_16x16x32_bf16(ap, bv0, oacc[0], 0, 0, 0);
            oacc[1] = __builtin_amdgcn_mfma_f32_16x16x32_bf16(ap, bv1, oacc[1], 0, 0, 0);
        }
    }
    __syncthreads();

    int part = b * NSPLIT + sp;
    if (t < qlim) {
        mpart[((size_t)part * HH + h) * BQ + q0 + t] = m_s[t];
        lpart[((size_t)part * HH + h) * BQ + q0 + t] = l_s[t];
    }
#pragma unroll
    for (int nd = 0; nd < 2; nd++) {
#pragma unroll
        for (int r = 0; r < 4; r++) {
            int q = w * 16 + quad * 4 + r;
            if (q < qlim)
                Opart[((size_t)part * BQ + q0 + q) * DD + h * HDD + nd * 16 + fr] = oacc[nd][r];
        }
    }
}

// ---------------- self-attention (S=Q=100), MFMA single-pass ----------------
__global__ __launch_bounds__(256) void self_attn_mfma(
        const unsigned short* __restrict__ qkv, unsigned short* __restrict__ Out) {
    __shared__ unsigned short Qs[128][40];
    __shared__ unsigned short Vt[HDD][136];
    __shared__ unsigned short Ps[112][136];
    __shared__ float red[112][17];
    __shared__ float m_s[112], l_s[112];

    const int h = blockIdx.x, b = blockIdx.y;
    const int t = threadIdx.x;
    const int w = t >> 6, lane = t & 63;
    const int fr = lane & 15, quad = lane >> 4;

    {
        int r = t >> 1, half = t & 1;
        uint4 z = {0, 0, 0, 0};
        uint4 p0 = z, p1 = z, v0 = z, v1 = z;
        if (r < BQ) {
            const unsigned short* qp = qkv + (size_t)(b * BQ + r) * 768 + h * HDD + half * 16;
            p0 = *(const uint4*)qp;
            p1 = *(const uint4*)(qp + 8);
            const unsigned short* vp = qp + 512;
            v0 = *(const uint4*)vp;
            v1 = *(const uint4*)(vp + 8);
        }
        *(uint4*)&Qs[r][half * 16] = p0;
        *(uint4*)&Qs[r][half * 16 + 8] = p1;
        union { uint4 u; unsigned short s[8]; } a, c;
        a.u = v0; c.u = v1;
#pragma unroll
        for (int j = 0; j < 8; j++) Vt[half * 16 + j][r] = a.s[j];
#pragma unroll
        for (int j = 0; j < 8; j++) Vt[half * 16 + 8 + j][r] = c.s[j];
    }
    __syncthreads();

    bf16x8 af[2];
#pragma unroll
    for (int mt = 0; mt < 2; mt++) {
        int s = w * 32 + mt * 16 + fr;
        bf16x8 kz = {0, 0, 0, 0, 0, 0, 0, 0};
        af[mt] = kz;
        if (s < BQ)
            af[mt] = *(const bf16x8*)(qkv + (size_t)(b * BQ + s) * 768 + 256 + h * HDD + quad * 8);
    }
    f32x4 st[2][7];
#pragma unroll
    for (int nt = 0; nt < 7; nt++) {
        bf16x8 bq = *(const bf16x8*)&Qs[nt * 16 + fr][quad * 8];
#pragma unroll
        for (int mt = 0; mt < 2; mt++) {
            f32x4 z = {0.f, 0.f, 0.f, 0.f};
            st[mt][nt] = __builtin_amdgcn_mfma_f32_16x16x32_bf16(af[mt], bq, z, 0, 0, 0);
        }
    }

    float pmax[7];
#pragma unroll
    for (int nt = 0; nt < 7; nt++) {
        pmax[nt] = -1e30f;
#pragma unroll
        for (int mt = 0; mt < 2; mt++)
#pragma unroll
            for (int r = 0; r < 4; r++) {
                int s = w * 32 + mt * 16 + quad * 4 + r;
                float v = st[mt][nt][r];
                if (s >= BQ) v = -1e30f;
                st[mt][nt][r] = v;
                pmax[nt] = fmaxf(pmax[nt], v);
            }
        red[nt * 16 + fr][w * 4 + quad] = pmax[nt];
    }
    __syncthreads();
    if (t < 112) {
        float m = -1e30f;
#pragma unroll
        for (int k = 0; k < 16; k++) m = fmaxf(m, red[t][k]);
        m_s[t] = m;
    }
    __syncthreads();

    float psum[7];
#pragma unroll
    for (int nt = 0; nt < 7; nt++) {
        float mrow = m_s[nt * 16 + fr];
        psum[nt] = 0.f;
#pragma unroll
        for (int mt = 0; mt < 2; mt++) {
            float p0 = __expf(st[mt][nt][0] - mrow);
            float p1 = __expf(st[mt][nt][1] - mrow);
            float p2 = __expf(st[mt][nt][2] - mrow);
            float p3 = __expf(st[mt][nt][3] - mrow);
            psum[nt] += p0 + p1 + p2 + p3;
            uint2 pk;
            pk.x = pkbf(p0, p1);
            pk.y = pkbf(p2, p3);
            *(uint2*)&Ps[nt * 16 + fr][w * 32 + mt * 16 + quad * 4] = pk;
        }
        red[nt * 16 + fr][w * 4 + quad] = psum[nt];
    }
    __syncthreads();
    if (t < 112) {
        float s = 0.f;
#pragma unroll
        for (int k = 0; k < 16; k++) s += red[t][k];
        l_s[t] = s;
    }
    __syncthreads();

    f32x4 oacc[2][2] = {};
#pragma unroll
    for (int ti = 0; ti < 2; ti++) {
        int qt = w + ti * 4;
        if (qt < 7) {
#pragma unroll
            for (int k0 = 0; k0 < 128; k0 += 32) {
                bf16x8 ap = *(const bf16x8*)&Ps[qt * 16 + fr][k0 + quad * 8];
                bf16x8 bv0 = *(const bf16x8*)&Vt[fr][k0 + quad * 8];
                bf16x8 bv1 = *(const bf16x8*)&Vt[16 + fr][k0 + quad * 8];
                oacc[ti][0] = __builtin_amdgcn_mfma_f32_16x16x32_bf16(ap, bv0, oacc[ti][0], 0, 0, 0);
                oacc[ti][1] = __builtin_amdgcn_mfma_f32_16x16x32_bf16(ap, bv1, oacc[ti][1], 0, 0, 0);
            }
        }
    }
#pragma unroll
    for (int ti = 0; ti < 2; ti++) {
        int qt = w + ti * 4;
        if (qt < 7) {
#pragma unroll
            for (int nd = 0; nd < 2; nd++) {
#pragma unroll
                for (int r = 0; r < 4; r++) {
                    int q = qt * 16 + quad * 4 + r;
                    if (q < BQ) {
                        float inv = 1.0f / l_s[q];
                        Out[(size_t)(b * BQ + q) * DD + h * HDD + nd * 16 + fr] =
                            f2bf(oacc[ti][nd][r] * inv);
                    }
                }
            }
        }
    }
}

extern "C" void kernel_launch(void* const* d_in, const int* in_sizes, int n_in,
                              void* d_out, int out_size, void* d_ws, size_t ws_size,
                              hipStream_t stream) {
    const float* queries    = (const float*)d_in[0];
    const float* pixel_feat = (const float*)d_in[1];
    const float* prev_mask  = (const float*)d_in[2];
    const float* cross_in_w  = (const float*)d_in[3];
    const float* cross_in_b  = (const float*)d_in[4];
    const float* cross_out_w = (const float*)d_in[5];
    const float* cross_out_b = (const float*)d_in[6];
    const float* self_in_w   = (const float*)d_in[7];
    const float* self_in_b   = (const float*)d_in[8];
    const float* self_out_w  = (const float*)d_in[9];
    const float* self_out_b  = (const float*)d_in[10];
    const float* ln_cross_g  = (const float*)d_in[11];
    const float* ln_cross_b  = (const float*)d_in[12];
    const float* ln_self_g   = (const float*)d_in[13];
    const float* ln_self_b   = (const float*)d_in[14];
    const float* ln_ffn_g    = (const float*)d_in[15];
    const float* ln_ffn_b    = (const float*)d_in[16];
    const float* ffn_w1 = (const float*)d_in[17];
    const float* ffn_b1 = (const float*)d_in[18];
    const float* ffn_w2 = (const float*)d_in[19];
    const float* ffn_b2 = (const float*)d_in[20];
    float* out = (float*)d_out;

    const int NQ = SB * BQ;        // 800
    const int NK = SB * SS;        // 32768

    float* ws = (float*)d_ws;
    unsigned* Mbits = (unsigned*)ws;   ws += (size_t)NQ * 128;
    unsigned short* q_crossb = (unsigned short*)ws;  ws += (size_t)NQ * DD;  // bf16
    unsigned short* Kbk = (unsigned short*)ws;
    ws += (size_t)NK * DD / 2;
    unsigned short* Vbk = (unsigned short*)ws;
    ws += (size_t)NK * DD / 2;
    float* queries1 = ws;              ws += (size_t)NQ * DD;
    unsigned short* qkvb = (unsigned short*)ws;      ws += (size_t)NQ * 3 * DD;  // bf16
    unsigned short* attn2b = (unsigned short*)ws;    ws += (size_t)NQ * DD;      // bf16
    float* queries2 = ws;              ws += (size_t)NQ * DD;
    unsigned short* Hbf = (unsigned short*)ws;       ws += (size_t)NQ * 4 * DD;  // bf16
    float* Csplit   = ws;              ws += (size_t)4 * MROWS * DD;
    float* Opart    = ws;              ws += (size_t)SB * NSPLIT * BQ * DD;
    float* mpart    = ws;              ws += (size_t)SB * NSPLIT * HH * BQ;
    float* lpart    = ws;              ws += (size_t)SB * NSPLIT * HH * BQ;
    unsigned short* wbf = (unsigned short*)ws;   // bf16 weights, WTOT shorts
    ws += WTOT / 2;
    unsigned short* Abf = (unsigned short*)ws;   // pixel_feat bf16

    // ---- weight + pixel_feat pre-conversion to bf16 ----
    wprep<<<4608, 256, 0, stream>>>(
        cross_in_w, self_in_w, cross_out_w, self_out_w, ffn_w1, ffn_w2,
        pixel_feat, wbf, Abf);

    // ---- stage1: KV proj + maskpack + LN/Q-proj (one dispatch) ----
    stage1<<<1874, 256, 0, stream>>>(
        queries, ln_cross_g, ln_cross_b, wbf, cross_in_b, q_crossb,
        Abf, Kbk, Vbk, prev_mask, Mbits);

    // ---- cross attention ----
    cross_attn_mfma<<<dim3(2, HH, SB * NSPLIT), 256, 0, stream>>>(
        q_crossb, Kbk, Vbk, Mbits, Opart, mpart, lpart);
    comb_gemm<<<dim3(8, 25), 64, 0, stream>>>(
        Opart, mpart, lpart, wbf + WOFF_COW, cross_out_b, queries, queries1);

    // ---- self attention ----
    ln_gemm<3><<<dim3(24, 25), 64, 0, stream>>>(
        queries1, ln_self_g, ln_self_b, wbf + WOFF_SIW, self_in_b, nullptr,
        nullptr, qkvb, 3 * DD);
    self_attn_mfma<<<dim3(HH, SB), 256, 0, stream>>>(qkvb, attn2b);
    gemm_skinny2<256, 1, 2><<<dim3(8, 25), 64, 0, stream>>>(
        attn2b, wbf + WOFF_SOW, self_out_b, queries1, queries2, nullptr, DD);

    // ---- FFN ----
    ln_gemm<1><<<dim3(32, 25), 64, 0, stream>>>(
        queries2, ln_ffn_g, ln_ffn_b, wbf + WOFF_F1, ffn_b1, nullptr,
        nullptr, Hbf, 4 * DD);
    gemm_skinny2<1024, 4, 2><<<dim3(8, 25, 4), 64, 0, stream>>>(
        Hbf, wbf + WOFF_F2, ffn_b2, nullptr, nullptr, Csplit, DD);
    gemm_combine<4, 2><<<MROWS, 256, 0, stream>>>(
        Csplit, ffn_b2, queries2, out, DD);
}

// Round 10
// 224.466 us; speedup vs baseline: 1.0191x; 1.0191x over previous
//
#include <hip/hip_runtime.h>
#include <hip/hip_bf16.h>
#include <math.h>

#define BQ 100
#define SB 8
#define SS 4096
#define DD 256
#define HH 8
#define HDD 32
#define NSPLIT 4
#define SCHUNK (SS / NSPLIT)   // 1024
#define MROWS 800              // SB*BQ

typedef __attribute__((ext_vector_type(8))) short bf16x8;
typedef __attribute__((ext_vector_type(4))) float f32x4;

__device__ inline unsigned short f2bf(float f) {
    union { float f; unsigned u; } v; v.f = f;
    unsigned r = v.u + 0x7fff + ((v.u >> 16) & 1);
    return (unsigned short)(r >> 16);
}

// HW packed fp32x2 -> bf16x2 (v_cvt_pk_bf16_f32 on gfx950), RNE
__device__ inline unsigned pkbf(float x, float y) {
    union { __hip_bfloat162 h; unsigned u; } c;
    c.h = __float22bfloat162_rn(make_float2(x, y));
    return c.u;
}

// async global->LDS, 16B per lane.
typedef __attribute__((address_space(1))) const void gas_void;
typedef __attribute__((address_space(3))) void las_void;
__device__ inline void gl_lds16(const unsigned short* g, unsigned short* l) {
    __builtin_amdgcn_global_load_lds((gas_void*)g, (las_void*)l, 16, 0, 0);
}

#define TM 128
#define TN 128
#define QSCALE 0.17677669529663687f

// bf16 weight workspace offsets (in shorts)
#define WOFF_CW   0          // cross_in_w  768x256
#define WOFF_SIW  196608     // self_in_w   768x256
#define WOFF_COW  393216     // cross_out_w 256x256
#define WOFF_SOW  458752     // self_out_w  256x256
#define WOFF_F1   524288     // ffn_w1     1024x256
#define WOFF_F2   786432     // ffn_w2      256x1024
#define WTOT      1048576

// ============ wprep: weights + pixel_feat -> bf16 (once / iter) ============
__global__ __launch_bounds__(256) void wprep(
        const float* __restrict__ cw, const float* __restrict__ siw,
        const float* __restrict__ cow, const float* __restrict__ sow,
        const float* __restrict__ f1, const float* __restrict__ f2,
        const float* __restrict__ pix,
        unsigned short* __restrict__ o, unsigned short* __restrict__ abf) {
    int b = blockIdx.x;
    int t = threadIdx.x;
    if (b >= 512) {
        size_t off = (size_t)(b - 512) * 2048 + (size_t)t * 8;
        const float* p = pix + off;
        float4 a = *(const float4*)p;
        float4 c = *(const float4*)(p + 4);
        uint4 pk;
        pk.x = pkbf(a.x, a.y); pk.y = pkbf(a.z, a.w);
        pk.z = pkbf(c.x, c.y); pk.w = pkbf(c.z, c.w);
        *(uint4*)(abf + off) = pk;
        return;
    }
    const float* src; size_t so, doff;
    if (b < 96)       { src = cw;  so = (size_t)b * 2048;         doff = WOFF_CW; }
    else if (b < 192) { src = siw; so = (size_t)(b - 96) * 2048;  doff = WOFF_SIW; }
    else if (b < 224) { src = cow; so = (size_t)(b - 192) * 2048; doff = WOFF_COW; }
    else if (b < 256) { src = sow; so = (size_t)(b - 224) * 2048; doff = WOFF_SOW; }
    else if (b < 384) { src = f1;  so = (size_t)(b - 256) * 2048; doff = WOFF_F1; }
    else              { src = f2;  so = (size_t)(b - 384) * 2048; doff = WOFF_F2; }
    const float* p = src + so + (size_t)t * 8;
    float4 a = *(const float4*)p;
    float4 c = *(const float4*)(p + 4);
    uint4 pk;
    pk.x = pkbf(a.x, a.y); pk.y = pkbf(a.z, a.w);
    pk.z = pkbf(c.x, c.y); pk.w = pkbf(c.z, c.w);
    *(uint4*)(o + doff + so + (size_t)t * 8) = pk;
}

// ============ stage1: fused {KV projection | maskpack | LN+Q-projection} ====
// q_cross bf16 PRE-SCALED by 1/sqrt(HD).
__global__ __launch_bounds__(256, 3) void stage1(
        const float* __restrict__ queries,
        const float* __restrict__ ln_g, const float* __restrict__ ln_b,
        const unsigned short* __restrict__ wbf,
        const float* __restrict__ cb,
        unsigned short* __restrict__ q_cross,
        const unsigned short* __restrict__ Abf,
        unsigned short* __restrict__ Kb, unsigned short* __restrict__ Vb,
        const float* __restrict__ mask, unsigned* __restrict__ Mbits) {
    __shared__ __align__(16) char smem[32768];
    const int bid = blockIdx.x;
    const int t = threadIdx.x;

    if (bid < 1024) {
        unsigned short* Sbuf = (unsigned short*)smem;  // 2 x (A 4096 + B 4096)
        const unsigned short* Wb = wbf + (size_t)DD * DD;
        const float* bias = cb + DD;
        int xcd = bid & 7, idx = bid >> 3;
        int mtile = xcd + 8 * (idx >> 2);
        int ntl = idx & 3;
        int m0 = mtile * TM, n0 = ntl * TN;
        int wave = t >> 6, lane = t & 63;
        int wm = (wave & 1) * 64, wn = (wave >> 1) * 64;
        int fr = lane & 15, quad = lane >> 4;
        f32x4 acc[4][4] = {};

        const int c0 = t, c1 = 256 + t;
        const int r0 = c0 >> 2, r1 = c1 >> 2;
        const int cc0 = (c0 & 3) ^ ((r0 >> 1) & 3);
        const int cc1 = (c1 & 3) ^ ((r1 >> 1) & 3);

        gl_lds16(Abf + (size_t)(m0 + r0) * DD + cc0 * 8, Sbuf + c0 * 8);
        gl_lds16(Abf + (size_t)(m0 + r1) * DD + cc1 * 8, Sbuf + c1 * 8);
        gl_lds16(Wb + (size_t)(n0 + r0) * DD + cc0 * 8, Sbuf + 4096 + c0 * 8);
        gl_lds16(Wb + (size_t)(n0 + r1) * DD + cc1 * 8, Sbuf + 4096 + c1 * 8);
        __syncthreads();

#pragma unroll
        for (int ks = 0; ks < 8; ks++) {
            unsigned short* Ab = Sbuf + (ks & 1) * 8192;
            unsigned short* Bb = Ab + 4096;
            if (ks < 7) {
                unsigned short* An = Sbuf + ((ks + 1) & 1) * 8192;
                unsigned short* Bn = An + 4096;
                int k0 = (ks + 1) * 32;
                gl_lds16(Abf + (size_t)(m0 + r0) * DD + k0 + cc0 * 8, An + c0 * 8);
                gl_lds16(Abf + (size_t)(m0 + r1) * DD + k0 + cc1 * 8, An + c1 * 8);
                gl_lds16(Wb + (size_t)(n0 + r0) * DD + k0 + cc0 * 8, Bn + c0 * 8);
                gl_lds16(Wb + (size_t)(n0 + r1) * DD + k0 + cc1 * 8, Bn + c1 * 8);
            }
            bf16x8 af[4], bv[4];
#pragma unroll
            for (int mi = 0; mi < 4; mi++) {
                int row = wm + mi * 16 + fr;
                int j = quad ^ ((row >> 1) & 3);
                af[mi] = *(const bf16x8*)(Ab + row * 32 + j * 8);
            }
#pragma unroll
            for (int ni = 0; ni < 4; ni++) {
                int row = wn + ni * 16 + fr;
                int j = quad ^ ((row >> 1) & 3);
                bv[ni] = *(const bf16x8*)(Bb + row * 32 + j * 8);
            }
#pragma unroll
            for (int mi = 0; mi < 4; mi++) {
                acc[mi][0] = __builtin_amdgcn_mfma_f32_16x16x32_bf16(af[mi], bv[0], acc[mi][0], 0, 0, 0);
                acc[mi][1] = __builtin_amdgcn_mfma_f32_16x16x32_bf16(af[mi], bv[1], acc[mi][1], 0, 0, 0);
                acc[mi][2] = __builtin_amdgcn_mfma_f32_16x16x32_bf16(af[mi], bv[2], acc[mi][2], 0, 0, 0);
                acc[mi][3] = __builtin_amdgcn_mfma_f32_16x16x32_bf16(af[mi], bv[3], acc[mi][3], 0, 0, 0);
            }
            __syncthreads();
        }
#pragma unroll
        for (int ni = 0; ni < 4; ni++) {
            int n = n0 + wn + ni * 16 + fr;
            float bv = bias[n];
            int hh = (n >> 5) & 7, d = n & 31;
            if (n < 256) {                         // K: [b,h,s,d]
#pragma unroll
                for (int mi = 0; mi < 4; mi++) {
#pragma unroll
                    for (int r = 0; r < 4; r++) {
                        int m = m0 + wm + mi * 16 + quad * 4 + r;
                        int bb = m >> 12, s = m & (SS - 1);
                        Kb[((((size_t)bb * HH + hh) * SS + s) << 5) + d] =
                            f2bf(acc[mi][ni][r] + bv);
                    }
                }
            } else {                               // V: [b,h,d,s], 8B stores
#pragma unroll
                for (int mi = 0; mi < 4; mi++) {
                    int m = m0 + wm + mi * 16 + quad * 4;
                    int bb = m >> 12, s = m & (SS - 1);
                    union { unsigned short u[4]; uint2 v; } pk;
#pragma unroll
                    for (int r = 0; r < 4; r++)
                        pk.u[r] = f2bf(acc[mi][ni][r] + bv);
                    *(uint2*)&Vb[(((size_t)bb * HH + hh) * 32 + d) * SS + s] = pk.v;
                }
            }
        }
    } else if (bid < 1824) {
        int row = bid - 1024;
        unsigned* words = (unsigned*)smem;
        unsigned* orred = (unsigned*)(smem + 512);
        int w = t >> 6, lane = t & 63;
        const float* mp = mask + (size_t)row * SS + lane;
        float mv[16];
#pragma unroll
        for (int i = 0; i < 16; i++) mv[i] = mp[(w * 16 + i) * 64];
        unsigned lor = 0;
#pragma unroll
        for (int i = 0; i < 16; i++) {
            unsigned long long bal = __ballot(mv[i] > 0.f);
            if (lane == 0) {
                words[(w * 16 + i) * 2] = (unsigned)bal;
                words[(w * 16 + i) * 2 + 1] = (unsigned)(bal >> 32);
            }
            lor |= (unsigned)(bal | (bal >> 32));
        }
        if (lane == 0) orred[w] = lor;
        __syncthreads();
        unsigned anyv = orred[0] | orred[1] | orred[2] | orred[3];
        if (t < 128) Mbits[(size_t)row * 128 + t] = anyv ? words[t] : 0xFFFFFFFFu;
    } else {
        typedef unsigned short (*arow_t)[264];
        arow_t Aq = (arow_t)smem;
        float* mu_s = (float*)(smem + 16896);
        float* rs_s = mu_s + 32;
        float (*prt)[8][2] = (float(*)[8][2])(rs_s + 32);
        int idx = bid - 1824;
        int nq = idx & 1, my = idx >> 1;
        int m0 = my * 32;
        int row = t & 31, cs = t >> 5;
        const float* xp = queries + (size_t)(m0 + row) * DD + cs * 32;
        float s = 0.f, ss = 0.f;
#pragma unroll
        for (int c = 0; c < 32; c += 4) {
            float4 v = *(const float4*)(xp + c);
            s += v.x + v.y + v.z + v.w;
            ss += v.x * v.x + v.y * v.y + v.z * v.z + v.w * v.w;
        }
        prt[row][cs][0] = s; prt[row][cs][1] = ss;
        __syncthreads();
        if (t < 32) {
            float sum = 0.f, sq = 0.f;
#pragma unroll
            for (int k = 0; k < 8; k++) { sum += prt[t][k][0]; sq += prt[t][k][1]; }
            float mu = sum * (1.0f / DD);
            float var = sq * (1.0f / DD) - mu * mu;
            mu_s[t] = mu;
            rs_s[t] = rsqrtf(var + 1e-5f);
        }
        __syncthreads();
        {
            float mu = mu_s[row], r = rs_s[row];
            int col0 = cs * 32;
#pragma unroll
            for (int c = 0; c < 32; c += 8) {
                int col = col0 + c;
                float4 v0 = *(const float4*)(xp + c);
                float4 v1 = *(const float4*)(xp + c + 4);
                float4 g0 = *(const float4*)(ln_g + col);
                float4 g1 = *(const float4*)(ln_g + col + 4);
                float4 b0 = *(const float4*)(ln_b + col);
                float4 b1 = *(const float4*)(ln_b + col + 4);
                uint4 pk;
                pk.x = pkbf((v0.x - mu) * r * g0.x + b0.x, (v0.y - mu) * r * g0.y + b0.y);
                pk.y = pkbf((v0.z - mu) * r * g0.z + b0.z, (v0.w - mu) * r * g0.w + b0.w);
                pk.z = pkbf((v1.x - mu) * r * g1.x + b1.x, (v1.y - mu) * r * g1.y + b1.y);
                pk.w = pkbf((v1.z - mu) * r * g1.z + b1.z, (v1.w - mu) * r * g1.w + b1.w);
                *(uint4*)&Aq[row][col] = pk;
            }
        }
        __syncthreads();
        int w = t >> 6, lane = t & 63;
        int fr = lane & 15, quad = lane >> 4;
        int n0 = nq * 128 + w * 32;
        f32x4 acc[2][2] = {};
        const unsigned short* Wq0 = wbf + (size_t)(n0 + fr) * DD + quad * 8;
        const unsigned short* Wq1 = Wq0 + (size_t)16 * DD;
#pragma unroll
        for (int k0 = 0; k0 < DD; k0 += 32) {
            bf16x8 a0 = *(const bf16x8*)&Aq[fr][k0 + quad * 8];
            bf16x8 a1 = *(const bf16x8*)&Aq[16 + fr][k0 + quad * 8];
            bf16x8 w0 = *(const bf16x8*)(Wq0 + k0);
            bf16x8 w1 = *(const bf16x8*)(Wq1 + k0);
            acc[0][0] = __builtin_amdgcn_mfma_f32_16x16x32_bf16(a0, w0, acc[0][0], 0, 0, 0);
            acc[0][1] = __builtin_amdgcn_mfma_f32_16x16x32_bf16(a0, w1, acc[0][1], 0, 0, 0);
            acc[1][0] = __builtin_amdgcn_mfma_f32_16x16x32_bf16(a1, w0, acc[1][0], 0, 0, 0);
            acc[1][1] = __builtin_amdgcn_mfma_f32_16x16x32_bf16(a1, w1, acc[1][1], 0, 0, 0);
        }
#pragma unroll
        for (int ni = 0; ni < 2; ni++) {
            int n = n0 + ni * 16 + fr;
            float bv = cb[n];
#pragma unroll
            for (int mi = 0; mi < 2; mi++) {
#pragma unroll
                for (int r = 0; r < 4; r++) {
                    int m = m0 + mi * 16 + quad * 4 + r;
                    q_cross[(size_t)m * DD + n] =
                        f2bf((acc[mi][ni][r] + bv) * QSCALE);
                }
            }
        }
    }
}

// ---------------- fused LayerNorm + one-wave MFMA GEMM ----------------------
// MODE 1: bf16 out, GELU. MODE 3: bf16 out, Q-scale folded on cols < 256.
template<int MODE>
__global__ __launch_bounds__(64, 4) void ln_gemm(
        const float* __restrict__ X, const float* __restrict__ gam,
        const float* __restrict__ bet,
        const unsigned short* __restrict__ W, const float* __restrict__ bias,
        const float* __restrict__ res,
        float* __restrict__ C, unsigned short* __restrict__ Cb, int N) {
    __shared__ unsigned short As[32][264];
    __shared__ float mu_s[32], rs_s[32];
    __shared__ float prt[32][2][2];
    const int t = threadIdx.x;
    const int fr = t & 15, quad = t >> 4;
    const int m0 = blockIdx.y * 32, n0 = blockIdx.x * 32;
    const int row = t & 31, half = t >> 5;

    const float* xp = X + (size_t)(m0 + row) * DD + half * 128;
    float s = 0.f, ss = 0.f;
#pragma unroll
    for (int c = 0; c < 128; c += 4) {
        float4 v = *(const float4*)(xp + c);
        s += v.x + v.y + v.z + v.w;
        ss += v.x * v.x + v.y * v.y + v.z * v.z + v.w * v.w;
    }
    prt[row][half][0] = s;
    prt[row][half][1] = ss;
    __syncthreads();
    if (t < 32) {
        float sum = prt[t][0][0] + prt[t][1][0];
        float sq  = prt[t][0][1] + prt[t][1][1];
        float mu = sum * (1.0f / DD);
        float var = sq * (1.0f / DD) - mu * mu;
        mu_s[t] = mu;
        rs_s[t] = rsqrtf(var + 1e-5f);
    }
    __syncthreads();
    {
        float mu = mu_s[row], r = rs_s[row];
#pragma unroll
        for (int c = 0; c < 128; c += 8) {
            int col = half * 128 + c;
            float4 v0 = *(const float4*)(xp + c);
            float4 v1 = *(const float4*)(xp + c + 4);
            float4 g0 = *(const float4*)(gam + col);
            float4 g1 = *(const float4*)(gam + col + 4);
            float4 b0 = *(const float4*)(bet + col);
            float4 b1 = *(const float4*)(bet + col + 4);
            uint4 pk;
            pk.x = pkbf((v0.x - mu) * r * g0.x + b0.x, (v0.y - mu) * r * g0.y + b0.y);
            pk.y = pkbf((v0.z - mu) * r * g0.z + b0.z, (v0.w - mu) * r * g0.w + b0.w);
            pk.z = pkbf((v1.x - mu) * r * g1.x + b1.x, (v1.y - mu) * r * g1.y + b1.y);
            pk.w = pkbf((v1.z - mu) * r * g1.z + b1.z, (v1.w - mu) * r * g1.w + b1.w);
            *(uint4*)&As[row][col] = pk;
        }
    }
    __syncthreads();

    f32x4 acc[2][2] = {};
    const unsigned short* Wp0 = W + (size_t)(n0 + fr) * DD + quad * 8;
    const unsigned short* Wp1 = Wp0 + (size_t)16 * DD;
#pragma unroll
    for (int k0 = 0; k0 < DD; k0 += 32) {
        bf16x8 a0 = *(const bf16x8*)&As[fr][k0 + quad * 8];
        bf16x8 a1 = *(const bf16x8*)&As[16 + fr][k0 + quad * 8];
        bf16x8 w0 = *(const bf16x8*)(Wp0 + k0);
        bf16x8 w1 = *(const bf16x8*)(Wp1 + k0);
        acc[0][0] = __builtin_amdgcn_mfma_f32_16x16x32_bf16(a0, w0, acc[0][0], 0, 0, 0);
        acc[0][1] = __builtin_amdgcn_mfma_f32_16x16x32_bf16(a0, w1, acc[0][1], 0, 0, 0);
        acc[1][0] = __builtin_amdgcn_mfma_f32_16x16x32_bf16(a1, w0, acc[1][0], 0, 0, 0);
        acc[1][1] = __builtin_amdgcn_mfma_f32_16x16x32_bf16(a1, w1, acc[1][1], 0, 0, 0);
    }

#pragma unroll
    for (int ni = 0; ni < 2; ni++) {
        int n = n0 + ni * 16 + fr;
        float bv = bias[n];
#pragma unroll
        for (int mi = 0; mi < 2; mi++) {
#pragma unroll
            for (int r = 0; r < 4; r++) {
                int m = m0 + mi * 16 + quad * 4 + r;
                float v = acc[mi][ni][r] + bv;
                if (MODE == 1) {
                    v = 0.5f * v * (1.0f + erff(v * 0.70710678118654752f));
                    Cb[(size_t)m * N + n] = f2bf(v);
                } else if (MODE == 2) {
                    v += res[(size_t)m * N + n];
                    C[(size_t)m * N + n] = v;
                } else if (MODE == 3) {
                    if (n < 256) v *= QSCALE;
                    Cb[(size_t)m * N + n] = f2bf(v);
                } else {
                    C[(size_t)m * N + n] = v;
                }
            }
        }
    }
}

// ---------------- fused split-S combine + output projection -----------------
__global__ __launch_bounds__(64, 4) void comb_gemm(
        const float* __restrict__ Opart, const float* __restrict__ mpart,
        const float* __restrict__ lpart,
        const unsigned short* __restrict__ W, const float* __restrict__ bias,
        const float* __restrict__ res,
        float* __restrict__ C) {
    __shared__ unsigned short As[32][264];
    const int t = threadIdx.x;
    const int fr = t & 15, quad = t >> 4;
    const int m0 = blockIdx.y * 32, n0 = blockIdx.x * 32;
    const int row = t & 31, half = t >> 5;

    {
        int m = m0 + row;
        int b = m / BQ, q = m % BQ;
#pragma unroll
        for (int h = half * 4; h < half * 4 + 4; h++) {
            float mv[NSPLIT], wsp[NSPLIT];
            float mstar = -1e30f;
#pragma unroll
            for (int sp = 0; sp < NSPLIT; sp++) {
                mv[sp] = mpart[((size_t)(b * NSPLIT + sp) * HH + h) * BQ + q];
                mstar = fmaxf(mstar, mv[sp]);
            }
            float lstar = 0.f;
#pragma unroll
            for (int sp = 0; sp < NSPLIT; sp++) {
                wsp[sp] = __expf(mv[sp] - mstar);
                lstar += lpart[((size_t)(b * NSPLIT + sp) * HH + h) * BQ + q] * wsp[sp];
            }
            float inv = 1.0f / lstar;
#pragma unroll
            for (int d = 0; d < HDD; d += 8) {
                float o[8] = {};
#pragma unroll
                for (int sp = 0; sp < NSPLIT; sp++) {
                    const float* op = Opart +
                        ((size_t)(b * NSPLIT + sp) * BQ + q) * DD + h * HDD + d;
                    float4 a = *(const float4*)op;
                    float4 b4 = *(const float4*)(op + 4);
                    o[0] += a.x * wsp[sp];  o[1] += a.y * wsp[sp];
                    o[2] += a.z * wsp[sp];  o[3] += a.w * wsp[sp];
                    o[4] += b4.x * wsp[sp]; o[5] += b4.y * wsp[sp];
                    o[6] += b4.z * wsp[sp]; o[7] += b4.w * wsp[sp];
                }
                uint4 pk;
                pk.x = pkbf(o[0] * inv, o[1] * inv);
                pk.y = pkbf(o[2] * inv, o[3] * inv);
                pk.z = pkbf(o[4] * inv, o[5] * inv);
                pk.w = pkbf(o[6] * inv, o[7] * inv);
                *(uint4*)&As[row][h * HDD + d] = pk;
            }
        }
    }
    __syncthreads();

    f32x4 acc[2][2] = {};
    const unsigned short* Wp0 = W + (size_t)(n0 + fr) * DD + quad * 8;
    const unsigned short* Wp1 = Wp0 + (size_t)16 * DD;
#pragma unroll
    for (int k0 = 0; k0 < DD; k0 += 32) {
        bf16x8 a0 = *(const bf16x8*)&As[fr][k0 + quad * 8];
        bf16x8 a1 = *(const bf16x8*)&As[16 + fr][k0 + quad * 8];
        bf16x8 w0 = *(const bf16x8*)(Wp0 + k0);
        bf16x8 w1 = *(const bf16x8*)(Wp1 + k0);
        acc[0][0] = __builtin_amdgcn_mfma_f32_16x16x32_bf16(a0, w0, acc[0][0], 0, 0, 0);
        acc[0][1] = __builtin_amdgcn_mfma_f32_16x16x32_bf16(a0, w1, acc[0][1], 0, 0, 0);
        acc[1][0] = __builtin_amdgcn_mfma_f32_16x16x32_bf16(a1, w0, acc[1][0], 0, 0, 0);
        acc[1][1] = __builtin_amdgcn_mfma_f32_16x16x32_bf16(a1, w1, acc[1][1], 0, 0, 0);
    }

#pragma unroll
    for (int ni = 0; ni < 2; ni++) {
        int n = n0 + ni * 16 + fr;
        float bv = bias[n];
#pragma unroll
        for (int mi = 0; mi < 2; mi++) {
#pragma unroll
            for (int r = 0; r < 4; r++) {
                int m = m0 + mi * 16 + quad * 4 + r;
                float v = acc[mi][ni][r] + bv + res[(size_t)m * DD + n];
                C[(size_t)m * DD + n] = v;
            }
        }
    }
}

// ---------------- one-wave MFMA GEMM: bf16 A, 32x32 tile (SPLITK=1 only) ----
template<int KK, int MODE>
__global__ __launch_bounds__(64, 4) void gemm_skinny2(
        const unsigned short* __restrict__ A, const unsigned short* __restrict__ W,
        const float* __restrict__ bias, const float* __restrict__ res,
        float* __restrict__ C, int N) {
    const int lane = threadIdx.x;
    const int fr = lane & 15, quad = lane >> 4;
    const int m0 = blockIdx.y * 32;
    const int n0 = blockIdx.x * 32;

    f32x4 acc[2][2] = {};
    const unsigned short* Ap0 = A + (size_t)(m0 + fr) * KK + quad * 8;
    const unsigned short* Ap1 = Ap0 + (size_t)16 * KK;
    const unsigned short* Wp0 = W + (size_t)(n0 + fr) * KK + quad * 8;
    const unsigned short* Wp1 = Wp0 + (size_t)16 * KK;

#pragma unroll
    for (int k0 = 0; k0 < KK; k0 += 32) {
        bf16x8 a0 = *(const bf16x8*)(Ap0 + k0);
        bf16x8 a1 = *(const bf16x8*)(Ap1 + k0);
        bf16x8 w0 = *(const bf16x8*)(Wp0 + k0);
        bf16x8 w1 = *(const bf16x8*)(Wp1 + k0);
        acc[0][0] = __builtin_amdgcn_mfma_f32_16x16x32_bf16(a0, w0, acc[0][0], 0, 0, 0);
        acc[0][1] = __builtin_amdgcn_mfma_f32_16x16x32_bf16(a0, w1, acc[0][1], 0, 0, 0);
        acc[1][0] = __builtin_amdgcn_mfma_f32_16x16x32_bf16(a1, w0, acc[1][0], 0, 0, 0);
        acc[1][1] = __builtin_amdgcn_mfma_f32_16x16x32_bf16(a1, w1, acc[1][1], 0, 0, 0);
    }

#pragma unroll
    for (int ni = 0; ni < 2; ni++) {
        int n = n0 + ni * 16 + fr;
        float bv = bias[n];
#pragma unroll
        for (int mi = 0; mi < 2; mi++) {
#pragma unroll
            for (int r = 0; r < 4; r++) {
                int m = m0 + mi * 16 + quad * 4 + r;
                float v = acc[mi][ni][r] + bv;
                if (MODE == 1) {
                    v = 0.5f * v * (1.0f + erff(v * 0.70710678118654752f));
                } else if (MODE == 2) {
                    v += res[(size_t)m * N + n];
                }
                C[(size_t)m * N + n] = v;
            }
        }
    }
}

// ---------------- FFN2: K=1024 split across 4 waves, LDS reduce, fused ------
// 200 blocks x 256 thr = 800 waves (same TLP as split-K-4 grid); removes the
// separate combine dispatch and the Csplit HBM round-trip.
__global__ __launch_bounds__(256) void ffn2_gemm(
        const unsigned short* __restrict__ Hbf,
        const unsigned short* __restrict__ W2, const float* __restrict__ b2,
        const float* __restrict__ res, float* __restrict__ out) {
    __shared__ float part[3][32][33];
    const int t = threadIdx.x;
    const int w = t >> 6, lane = t & 63;
    const int fr = lane & 15, quad = lane >> 4;
    const int m0 = blockIdx.y * 32, n0 = blockIdx.x * 32;

    f32x4 acc[2][2] = {};
    const unsigned short* Ap0 = Hbf + (size_t)(m0 + fr) * 1024 + w * 256 + quad * 8;
    const unsigned short* Ap1 = Ap0 + (size_t)16 * 1024;
    const unsigned short* Wp0 = W2 + (size_t)(n0 + fr) * 1024 + w * 256 + quad * 8;
    const unsigned short* Wp1 = Wp0 + (size_t)16 * 1024;
#pragma unroll
    for (int k0 = 0; k0 < 256; k0 += 32) {
        bf16x8 a0 = *(const bf16x8*)(Ap0 + k0);
        bf16x8 a1 = *(const bf16x8*)(Ap1 + k0);
        bf16x8 w0 = *(const bf16x8*)(Wp0 + k0);
        bf16x8 w1 = *(const bf16x8*)(Wp1 + k0);
        acc[0][0] = __builtin_amdgcn_mfma_f32_16x16x32_bf16(a0, w0, acc[0][0], 0, 0, 0);
        acc[0][1] = __builtin_amdgcn_mfma_f32_16x16x32_bf16(a0, w1, acc[0][1], 0, 0, 0);
        acc[1][0] = __builtin_amdgcn_mfma_f32_16x16x32_bf16(a1, w0, acc[1][0], 0, 0, 0);
        acc[1][1] = __builtin_amdgcn_mfma_f32_16x16x32_bf16(a1, w1, acc[1][1], 0, 0, 0);
    }

    if (w > 0) {
#pragma unroll
        for (int ni = 0; ni < 2; ni++)
#pragma unroll
            for (int mi = 0; mi < 2; mi++)
#pragma unroll
                for (int r = 0; r < 4; r++)
                    part[w - 1][mi * 16 + quad * 4 + r][ni * 16 + fr] = acc[mi][ni][r];
    }
    __syncthreads();
    if (w == 0) {
#pragma unroll
        for (int ni = 0; ni < 2; ni++) {
            int n = n0 + ni * 16 + fr;
            float bv = b2[n];
#pragma unroll
            for (int mi = 0; mi < 2; mi++) {
#pragma unroll
                for (int r = 0; r < 4; r++) {
                    int row = mi * 16 + quad * 4 + r;
                    int m = m0 + row;
                    int col = ni * 16 + fr;
                    float v = acc[mi][ni][r] + part[0][row][col] +
                              part[1][row][col] + part[2][row][col] +
                              bv + res[(size_t)m * DD + n];
                    out[(size_t)m * DD + n] = v;
                }
            }
        }
    }
}

// ---------------- MFMA flash cross-attention (round-8 version) --------------
#define QT 64
#define ST 128

__global__ __launch_bounds__(256) void cross_attn_mfma(
        const unsigned short* __restrict__ Qm,
        const unsigned short* __restrict__ Kb,
        const unsigned short* __restrict__ Vb,
        const unsigned* __restrict__ Mbits,
        float* __restrict__ Opart,
        float* __restrict__ mpart,
        float* __restrict__ lpart) {
    __shared__ unsigned short Qs[QT][40];
    __shared__ unsigned short Ks[ST][40];
    __shared__ unsigned short Vt[HDD][136];
    __shared__ unsigned short Ps[QT][136];
    __shared__ unsigned Mq[QT][4];
    __shared__ float4 redm[QT];
    __shared__ float4 reds[QT];
    __shared__ float m_s[QT], alpha_s[QT], l_s[QT];

    const int qb = blockIdx.x, h = blockIdx.y;
    const int b = blockIdx.z / NSPLIT, sp = blockIdx.z % NSPLIT;
    const int t = threadIdx.x;
    const int w = t >> 6, lane = t & 63;
    const int fr = lane & 15, quad = lane >> 4;
    const int q0 = qb * QT;
    const int qlim = min(BQ - q0, QT);

    {
        int q = t >> 2, c0 = (t & 3) * 8;
        uint4 pq = {0, 0, 0, 0};
        if (q < qlim)
            pq = *(const uint4*)(Qm + (size_t)(b * BQ + q0 + q) * DD + h * HDD + c0);
        *(uint4*)&Qs[q][c0] = pq;
        if (t < QT) { m_s[t] = -1e30f; l_s[t] = 0.f; }
    }

    f32x4 oacc[2] = {};
    const unsigned short* Kbase = Kb + (((size_t)(b * HH + h)) * SS << 5);
    const unsigned short* Vbase = Vb + (((size_t)(b * HH + h)) << 5) * SS;

    for (int s0 = sp * SCHUNK; s0 < (sp + 1) * SCHUNK; s0 += ST) {
        __syncthreads();                               // B1
        {
            int r = t >> 1, half = t & 1;
            const unsigned short* kp = Kbase + ((size_t)(s0 + r) << 5) + half * 16;
            *(uint4*)&Ks[r][half * 16] = *(const uint4*)kp;
            *(uint4*)&Ks[r][half * 16 + 8] = *(const uint4*)(kp + 8);
            int d = t >> 3, c = (t & 7) * 16;
            const unsigned short* vp = Vbase + (size_t)d * SS + s0 + c;
            *(uint4*)&Vt[d][c] = *(const uint4*)vp;
            *(uint4*)&Vt[d][c + 8] = *(const uint4*)(vp + 8);
        }
        {
            int q = t >> 2, wd = t & 3;
            unsigned mword = 0xFFFFFFFFu;
            if (q < qlim)
                mword = Mbits[(size_t)(b * BQ + q0 + q) * 128 + (s0 >> 5) + wd];
            Mq[q][wd] = mword;
        }
        __syncthreads();                               // B2

        bf16x8 af[2];
#pragma unroll
        for (int mt = 0; mt < 2; mt++)
            af[mt] = *(const bf16x8*)&Ks[w * 32 + mt * 16 + fr][quad * 8];
        f32x4 st[2][4];
#pragma unroll
        for (int nt = 0; nt < 4; nt++) {
            bf16x8 bq = *(const bf16x8*)&Qs[nt * 16 + fr][quad * 8];
#pragma unroll
            for (int mt = 0; mt < 2; mt++) {
                f32x4 z = {0.f, 0.f, 0.f, 0.f};
                st[mt][nt] = __builtin_amdgcn_mfma_f32_16x16x32_bf16(af[mt], bq, z, 0, 0, 0);
            }
        }

        float mo[4];
#pragma unroll
        for (int nt = 0; nt < 4; nt++) mo[nt] = m_s[nt * 16 + fr];

        float pmax[4];
#pragma unroll
        for (int nt = 0; nt < 4; nt++) {
            unsigned mword = Mq[nt * 16 + fr][w];
            pmax[nt] = -1e30f;
#pragma unroll
            for (int mt = 0; mt < 2; mt++)
#pragma unroll
                for (int r = 0; r < 4; r++) {
                    int bitpos = mt * 16 + quad * 4 + r;
                    float v = st[mt][nt][r];
                    if (!((mword >> bitpos) & 1u)) v -= 10000.f;
                    st[mt][nt][r] = v;
                    pmax[nt] = fmaxf(pmax[nt], v);
                }
        }
#pragma unroll
        for (int nt = 0; nt < 4; nt++) {
            pmax[nt] = fmaxf(pmax[nt], __shfl_xor(pmax[nt], 16));
            pmax[nt] = fmaxf(pmax[nt], __shfl_xor(pmax[nt], 32));
        }
        if (quad == 0) {
#pragma unroll
            for (int nt = 0; nt < 4; nt++)
                ((float*)&redm[nt * 16 + fr])[w] = pmax[nt];
        }
        __syncthreads();                               // B3

        float mn[4], al[4];
#pragma unroll
        for (int nt = 0; nt < 4; nt++) {
            float4 rr = redm[nt * 16 + fr];
            float mt4 = fmaxf(fmaxf(rr.x, rr.y), fmaxf(rr.z, rr.w));
            mn[nt] = fmaxf(mo[nt], mt4);
            al[nt] = __expf(mo[nt] - mn[nt]);
        }
        if (w == 0 && quad == 0) {
#pragma unroll
            for (int nt = 0; nt < 4; nt++) {
                m_s[nt * 16 + fr] = mn[nt];
                alpha_s[nt * 16 + fr] = al[nt];
            }
        }

        float psum[4];
#pragma unroll
        for (int nt = 0; nt < 4; nt++) {
            psum[nt] = 0.f;
#pragma unroll
            for (int mt = 0; mt < 2; mt++) {
                float p0 = __expf(st[mt][nt][0] - mn[nt]);
                float p1 = __expf(st[mt][nt][1] - mn[nt]);
                float p2 = __expf(st[mt][nt][2] - mn[nt]);
                float p3 = __expf(st[mt][nt][3] - mn[nt]);
                psum[nt] += p0 + p1 + p2 + p3;
                uint2 pk;
                pk.x = pkbf(p0, p1);
                pk.y = pkbf(p2, p3);
                *(uint2*)&Ps[nt * 16 + fr][w * 32 + mt * 16 + quad * 4] = pk;
            }
        }
#pragma unroll
        for (int nt = 0; nt < 4; nt++) {
            psum[nt] += __shfl_xor(psum[nt], 16);
            psum[nt] += __shfl_xor(psum[nt], 32);
        }
        if (quad == 0) {
#pragma unroll
            for (int nt = 0; nt < 4; nt++)
                ((float*)&reds[nt * 16 + fr])[w] = psum[nt];
        }
        __syncthreads();                               // B4

        if (w == 0 && quad == 0) {
#pragma unroll
            for (int nt = 0; nt < 4; nt++) {
                int q = nt * 16 + fr;
                float4 ssum = reds[q];
                l_s[q] = l_s[q] * al[nt] + (ssum.x + ssum.y + ssum.z + ssum.w);
            }
        }

#pragma unroll
        for (int r = 0; r < 4; r++) {
            float a = alpha_s[w * 16 + quad * 4 + r];
            oacc[0][r] *= a; oacc[1][r] *= a;
        }
#pragma unroll
        for (int k0 = 0; k0 < ST; k0 += 32) {
            bf16x8 ap = *(const bf16x8*)&Ps[w * 16 + fr][k0 + quad * 8];
            bf16x8 bv0 = *(const bf16x8*)&Vt[fr][k0 + quad * 8];
            bf16x8 bv1 = *(const bf16x8*)&Vt[16 + fr][k0 + quad * 8];
            oacc[0] = __builtin_amdgcn_mfma_f32_16x16x32_bf16(ap, bv0, oacc[0], 0, 0, 0);
            oacc[1] = __builtin_amdgcn_mfma_f32_16x16x32_bf16(ap, bv1, oacc[1], 0, 0, 0);
        }
    }
    __syncthreads();

    int part = b * NSPLIT + sp;
    if (t < qlim) {
        mpart[((size_t)part * HH + h) * BQ + q0 + t] = m_s[t];
        lpart[((size_t)part * HH + h) * BQ + q0 + t] = l_s[t];
    }
#pragma unroll
    for (int nd = 0; nd < 2; nd++) {
#pragma unroll
        for (int r = 0; r < 4; r++) {
            int q = w * 16 + quad * 4 + r;
            if (q < qlim)
                Opart[((size_t)part * BQ + q0 + q) * DD + h * HDD + nd * 16 + fr] = oacc[nd][r];
        }
    }
}

// ---------------- self-attention (S=Q=100), MFMA single-pass ----------------
__global__ __launch_bounds__(256) void self_attn_mfma(
        const unsigned short* __restrict__ qkv, unsigned short* __restrict__ Out) {
    __shared__ unsigned short Qs[128][40];
    __shared__ unsigned short Vt[HDD][136];
    __shared__ unsigned short Ps[112][136];
    __shared__ float red[112][17];
    __shared__ float m_s[112], l_s[112];

    const int h = blockIdx.x, b = blockIdx.y;
    const int t = threadIdx.x;
    const int w = t >> 6, lane = t & 63;
    const int fr = lane & 15, quad = lane >> 4;

    {
        int r = t >> 1, half = t & 1;
        uint4 z = {0, 0, 0, 0};
        uint4 p0 = z, p1 = z, v0 = z, v1 = z;
        if (r < BQ) {
            const unsigned short* qp = qkv + (size_t)(b * BQ + r) * 768 + h * HDD + half * 16;
            p0 = *(const uint4*)qp;
            p1 = *(const uint4*)(qp + 8);
            const unsigned short* vp = qp + 512;
            v0 = *(const uint4*)vp;
            v1 = *(const uint4*)(vp + 8);
        }
        *(uint4*)&Qs[r][half * 16] = p0;
        *(uint4*)&Qs[r][half * 16 + 8] = p1;
        union { uint4 u; unsigned short s[8]; } a, c;
        a.u = v0; c.u = v1;
#pragma unroll
        for (int j = 0; j < 8; j++) Vt[half * 16 + j][r] = a.s[j];
#pragma unroll
        for (int j = 0; j < 8; j++) Vt[half * 16 + 8 + j][r] = c.s[j];
    }
    __syncthreads();

    bf16x8 af[2];
#pragma unroll
    for (int mt = 0; mt < 2; mt++) {
        int s = w * 32 + mt * 16 + fr;
        bf16x8 kz = {0, 0, 0, 0, 0, 0, 0, 0};
        af[mt] = kz;
        if (s < BQ)
            af[mt] = *(const bf16x8*)(qkv + (size_t)(b * BQ + s) * 768 + 256 + h * HDD + quad * 8);
    }
    f32x4 st[2][7];
#pragma unroll
    for (int nt = 0; nt < 7; nt++) {
        bf16x8 bq = *(const bf16x8*)&Qs[nt * 16 + fr][quad * 8];
#pragma unroll
        for (int mt = 0; mt < 2; mt++) {
            f32x4 z = {0.f, 0.f, 0.f, 0.f};
            st[mt][nt] = __builtin_amdgcn_mfma_f32_16x16x32_bf16(af[mt], bq, z, 0, 0, 0);
        }
    }

    float pmax[7];
#pragma unroll
    for (int nt = 0; nt < 7; nt++) {
        pmax[nt] = -1e30f;
#pragma unroll
        for (int mt = 0; mt < 2; mt++)
#pragma unroll
            for (int r = 0; r < 4; r++) {
                int s = w * 32 + mt * 16 + quad * 4 + r;
                float v = st[mt][nt][r];
                if (s >= BQ) v = -1e30f;
                st[mt][nt][r] = v;
                pmax[nt] = fmaxf(pmax[nt], v);
            }
        red[nt * 16 + fr][w * 4 + quad] = pmax[nt];
    }
    __syncthreads();
    if (t < 112) {
        float m = -1e30f;
#pragma unroll
        for (int k = 0; k < 16; k++) m = fmaxf(m, red[t][k]);
        m_s[t] = m;
    }
    __syncthreads();

    float psum[7];
#pragma unroll
    for (int nt = 0; nt < 7; nt++) {
        float mrow = m_s[nt * 16 + fr];
        psum[nt] = 0.f;
#pragma unroll
        for (int mt = 0; mt < 2; mt++) {
            float p0 = __expf(st[mt][nt][0] - mrow);
            float p1 = __expf(st[mt][nt][1] - mrow);
            float p2 = __expf(st[mt][nt][2] - mrow);
            float p3 = __expf(st[mt][nt][3] - mrow);
            psum[nt] += p0 + p1 + p2 + p3;
            uint2 pk;
            pk.x = pkbf(p0, p1);
            pk.y = pkbf(p2, p3);
            *(uint2*)&Ps[nt * 16 + fr][w * 32 + mt * 16 + quad * 4] = pk;
        }
        red[nt * 16 + fr][w * 4 + quad] = psum[nt];
    }
    __syncthreads();
    if (t < 112) {
        float s = 0.f;
#pragma unroll
        for (int k = 0; k < 16; k++) s += red[t][k];
        l_s[t] = s;
    }
    __syncthreads();

    f32x4 oacc[2][2] = {};
#pragma unroll
    for (int ti = 0; ti < 2; ti++) {
        int qt = w + ti * 4;
        if (qt < 7) {
#pragma unroll
            for (int k0 = 0; k0 < 128; k0 += 32) {
                bf16x8 ap = *(const bf16x8*)&Ps[qt * 16 + fr][k0 + quad * 8];
                bf16x8 bv0 = *(const bf16x8*)&Vt[fr][k0 + quad * 8];
                bf16x8 bv1 = *(const bf16x8*)&Vt[16 + fr][k0 + quad * 8];
                oacc[ti][0] = __builtin_amdgcn_mfma_f32_16x16x32_bf16(ap, bv0, oacc[ti][0], 0, 0, 0);
                oacc[ti][1] = __builtin_amdgcn_mfma_f32_16x16x32_bf16(ap, bv1, oacc[ti][1], 0, 0, 0);
            }
        }
    }
#pragma unroll
    for (int ti = 0; ti < 2; ti++) {
        int qt = w + ti * 4;
        if (qt < 7) {
#pragma unroll
            for (int nd = 0; nd < 2; nd++) {
#pragma unroll
                for (int r = 0; r < 4; r++) {
                    int q = qt * 16 + quad * 4 + r;
                    if (q < BQ) {
                        float inv = 1.0f / l_s[q];
                        Out[(size_t)(b * BQ + q) * DD + h * HDD + nd * 16 + fr] =
                            f2bf(oacc[ti][nd][r] * inv);
                    }
                }
            }
        }
    }
}

extern "C" void kernel_launch(void* const* d_in, const int* in_sizes, int n_in,
                              void* d_out, int out_size, void* d_ws, size_t ws_size,
                              hipStream_t stream) {
    const float* queries    = (const float*)d_in[0];
    const float* pixel_feat = (const float*)d_in[1];
    const float* prev_mask  = (const float*)d_in[2];
    const float* cross_in_w  = (const float*)d_in[3];
    const float* cross_in_b  = (const float*)d_in[4];
    const float* cross_out_w = (const float*)d_in[5];
    const float* cross_out_b = (const float*)d_in[6];
    const float* self_in_w   = (const float*)d_in[7];
    const float* self_in_b   = (const float*)d_in[8];
    const float* self_out_w  = (const float*)d_in[9];
    const float* self_out_b  = (const float*)d_in[10];
    const float* ln_cross_g  = (const float*)d_in[11];
    const float* ln_cross_b  = (const float*)d_in[12];
    const float* ln_self_g   = (const float*)d_in[13];
    const float* ln_self_b   = (const float*)d_in[14];
    const float* ln_ffn_g    = (const float*)d_in[15];
    const float* ln_ffn_b    = (const float*)d_in[16];
    const float* ffn_w1 = (const float*)d_in[17];
    const float* ffn_b1 = (const float*)d_in[18];
    const float* ffn_w2 = (const float*)d_in[19];
    const float* ffn_b2 = (const float*)d_in[20];
    float* out = (float*)d_out;

    const int NQ = SB * BQ;        // 800
    const int NK = SB * SS;        // 32768

    float* ws = (float*)d_ws;
    unsigned* Mbits = (unsigned*)ws;   ws += (size_t)NQ * 128;
    unsigned short* q_crossb = (unsigned short*)ws;  ws += (size_t)NQ * DD;  // bf16
    unsigned short* Kbk = (unsigned short*)ws;
    ws += (size_t)NK * DD / 2;
    unsigned short* Vbk = (unsigned short*)ws;
    ws += (size_t)NK * DD / 2;
    float* queries1 = ws;              ws += (size_t)NQ * DD;
    unsigned short* qkvb = (unsigned short*)ws;      ws += (size_t)NQ * 3 * DD;  // bf16
    unsigned short* attn2b = (unsigned short*)ws;    ws += (size_t)NQ * DD;      // bf16
    float* queries2 = ws;              ws += (size_t)NQ * DD;
    unsigned short* Hbf = (unsigned short*)ws;       ws += (size_t)NQ * 4 * DD;  // bf16
    float* Opart    = ws;              ws += (size_t)SB * NSPLIT * BQ * DD;
    float* mpart    = ws;              ws += (size_t)SB * NSPLIT * HH * BQ;
    float* lpart    = ws;              ws += (size_t)SB * NSPLIT * HH * BQ;
    unsigned short* wbf = (unsigned short*)ws;   // bf16 weights, WTOT shorts
    ws += WTOT / 2;
    unsigned short* Abf = (unsigned short*)ws;   // pixel_feat bf16

    // ---- weight + pixel_feat pre-conversion to bf16 ----
    wprep<<<4608, 256, 0, stream>>>(
        cross_in_w, self_in_w, cross_out_w, self_out_w, ffn_w1, ffn_w2,
        pixel_feat, wbf, Abf);

    // ---- stage1: KV proj + maskpack + LN/Q-proj (one dispatch) ----
    stage1<<<1874, 256, 0, stream>>>(
        queries, ln_cross_g, ln_cross_b, wbf, cross_in_b, q_crossb,
        Abf, Kbk, Vbk, prev_mask, Mbits);

    // ---- cross attention ----
    cross_attn_mfma<<<dim3(2, HH, SB * NSPLIT), 256, 0, stream>>>(
        q_crossb, Kbk, Vbk, Mbits, Opart, mpart, lpart);
    comb_gemm<<<dim3(8, 25), 64, 0, stream>>>(
        Opart, mpart, lpart, wbf + WOFF_COW, cross_out_b, queries, queries1);

    // ---- self attention ----
    ln_gemm<3><<<dim3(24, 25), 64, 0, stream>>>(
        queries1, ln_self_g, ln_self_b, wbf + WOFF_SIW, self_in_b, nullptr,
        nullptr, qkvb, 3 * DD);
    self_attn_mfma<<<dim3(HH, SB), 256, 0, stream>>>(qkvb, attn2b);
    gemm_skinny2<256, 2><<<dim3(8, 25), 64, 0, stream>>>(
        attn2b, wbf + WOFF_SOW, self_out_b, queries1, queries2, DD);

    // ---- FFN ----
    ln_gemm<1><<<dim3(32, 25), 64, 0, stream>>>(
        queries2, ln_ffn_g, ln_ffn_b, wbf + WOFF_F1, ffn_b1, nullptr,
        nullptr, Hbf, 4 * DD);
    ffn2_gemm<<<dim3(8, 25), 256, 0, stream>>>(
        Hbf, wbf + WOFF_F2, ffn_b2, queries2, out);
}

// Round 11
// 224.096 us; speedup vs baseline: 1.0208x; 1.0016x over previous
//
#include <hip/hip_runtime.h>
#include <hip/hip_bf16.h>
#include <math.h>

#define BQ 100
#define SB 8
#define SS 4096
#define DD 256
#define HH 8
#define HDD 32
#define NSPLIT 4
#define SCHUNK (SS / NSPLIT)   // 1024
#define MROWS 800              // SB*BQ

typedef __attribute__((ext_vector_type(8))) short bf16x8;
typedef __attribute__((ext_vector_type(4))) float f32x4;

__device__ inline unsigned short f2bf(float f) {
    union { float f; unsigned u; } v; v.f = f;
    unsigned r = v.u + 0x7fff + ((v.u >> 16) & 1);
    return (unsigned short)(r >> 16);
}

// HW packed fp32x2 -> bf16x2 (v_cvt_pk_bf16_f32 on gfx950), RNE
__device__ inline unsigned pkbf(float x, float y) {
    union { __hip_bfloat162 h; unsigned u; } c;
    c.h = __float22bfloat162_rn(make_float2(x, y));
    return c.u;
}

// async global->LDS, 16B per lane.
typedef __attribute__((address_space(1))) const void gas_void;
typedef __attribute__((address_space(3))) void las_void;
__device__ inline void gl_lds16(const unsigned short* g, unsigned short* l) {
    __builtin_amdgcn_global_load_lds((gas_void*)g, (las_void*)l, 16, 0, 0);
}

#define TM 128
#define TN 128
#define QSCALE 0.17677669529663687f

// bf16 weight workspace offsets (in shorts)
#define WOFF_CW   0          // cross_in_w  768x256
#define WOFF_SIW  196608     // self_in_w   768x256
#define WOFF_COW  393216     // cross_out_w 256x256
#define WOFF_SOW  458752     // self_out_w  256x256
#define WOFF_F1   524288     // ffn_w1     1024x256
#define WOFF_F2   786432     // ffn_w2      256x1024
#define WTOT      1048576

// ============ wprep: weights + pixel_feat -> bf16 (once / iter) ============
__global__ __launch_bounds__(256) void wprep(
        const float* __restrict__ cw, const float* __restrict__ siw,
        const float* __restrict__ cow, const float* __restrict__ sow,
        const float* __restrict__ f1, const float* __restrict__ f2,
        const float* __restrict__ pix,
        unsigned short* __restrict__ o, unsigned short* __restrict__ abf) {
    int b = blockIdx.x;
    int t = threadIdx.x;
    if (b >= 512) {
        size_t off = (size_t)(b - 512) * 2048 + (size_t)t * 8;
        const float* p = pix + off;
        float4 a = *(const float4*)p;
        float4 c = *(const float4*)(p + 4);
        uint4 pk;
        pk.x = pkbf(a.x, a.y); pk.y = pkbf(a.z, a.w);
        pk.z = pkbf(c.x, c.y); pk.w = pkbf(c.z, c.w);
        *(uint4*)(abf + off) = pk;
        return;
    }
    const float* src; size_t so, doff;
    if (b < 96)       { src = cw;  so = (size_t)b * 2048;         doff = WOFF_CW; }
    else if (b < 192) { src = siw; so = (size_t)(b - 96) * 2048;  doff = WOFF_SIW; }
    else if (b < 224) { src = cow; so = (size_t)(b - 192) * 2048; doff = WOFF_COW; }
    else if (b < 256) { src = sow; so = (size_t)(b - 224) * 2048; doff = WOFF_SOW; }
    else if (b < 384) { src = f1;  so = (size_t)(b - 256) * 2048; doff = WOFF_F1; }
    else              { src = f2;  so = (size_t)(b - 384) * 2048; doff = WOFF_F2; }
    const float* p = src + so + (size_t)t * 8;
    float4 a = *(const float4*)p;
    float4 c = *(const float4*)(p + 4);
    uint4 pk;
    pk.x = pkbf(a.x, a.y); pk.y = pkbf(a.z, a.w);
    pk.z = pkbf(c.x, c.y); pk.w = pkbf(c.z, c.w);
    *(uint4*)(o + doff + so + (size_t)t * 8) = pk;
}

// ============ stage1: fused {KV projection | maskpack | LN+Q-projection} ====
// q_cross bf16 PRE-SCALED by 1/sqrt(HD).
__global__ __launch_bounds__(256, 3) void stage1(
        const float* __restrict__ queries,
        const float* __restrict__ ln_g, const float* __restrict__ ln_b,
        const unsigned short* __restrict__ wbf,
        const float* __restrict__ cb,
        unsigned short* __restrict__ q_cross,
        const unsigned short* __restrict__ Abf,
        unsigned short* __restrict__ Kb, unsigned short* __restrict__ Vb,
        const float* __restrict__ mask, unsigned* __restrict__ Mbits) {
    __shared__ __align__(16) char smem[32768];
    const int bid = blockIdx.x;
    const int t = threadIdx.x;

    if (bid < 1024) {
        unsigned short* Sbuf = (unsigned short*)smem;  // 2 x (A 4096 + B 4096)
        const unsigned short* Wb = wbf + (size_t)DD * DD;
        const float* bias = cb + DD;
        int xcd = bid & 7, idx = bid >> 3;
        int mtile = xcd + 8 * (idx >> 2);
        int ntl = idx & 3;
        int m0 = mtile * TM, n0 = ntl * TN;
        int wave = t >> 6, lane = t & 63;
        int wm = (wave & 1) * 64, wn = (wave >> 1) * 64;
        int fr = lane & 15, quad = lane >> 4;
        f32x4 acc[4][4] = {};

        const int c0 = t, c1 = 256 + t;
        const int r0 = c0 >> 2, r1 = c1 >> 2;
        const int cc0 = (c0 & 3) ^ ((r0 >> 1) & 3);
        const int cc1 = (c1 & 3) ^ ((r1 >> 1) & 3);

        gl_lds16(Abf + (size_t)(m0 + r0) * DD + cc0 * 8, Sbuf + c0 * 8);
        gl_lds16(Abf + (size_t)(m0 + r1) * DD + cc1 * 8, Sbuf + c1 * 8);
        gl_lds16(Wb + (size_t)(n0 + r0) * DD + cc0 * 8, Sbuf + 4096 + c0 * 8);
        gl_lds16(Wb + (size_t)(n0 + r1) * DD + cc1 * 8, Sbuf + 4096 + c1 * 8);
        __syncthreads();

#pragma unroll
        for (int ks = 0; ks < 8; ks++) {
            unsigned short* Ab = Sbuf + (ks & 1) * 8192;
            unsigned short* Bb = Ab + 4096;
            if (ks < 7) {
                unsigned short* An = Sbuf + ((ks + 1) & 1) * 8192;
                unsigned short* Bn = An + 4096;
                int k0 = (ks + 1) * 32;
                gl_lds16(Abf + (size_t)(m0 + r0) * DD + k0 + cc0 * 8, An + c0 * 8);
                gl_lds16(Abf + (size_t)(m0 + r1) * DD + k0 + cc1 * 8, An + c1 * 8);
                gl_lds16(Wb + (size_t)(n0 + r0) * DD + k0 + cc0 * 8, Bn + c0 * 8);
                gl_lds16(Wb + (size_t)(n0 + r1) * DD + k0 + cc1 * 8, Bn + c1 * 8);
            }
            bf16x8 af[4], bv[4];
#pragma unroll
            for (int mi = 0; mi < 4; mi++) {
                int row = wm + mi * 16 + fr;
                int j = quad ^ ((row >> 1) & 3);
                af[mi] = *(const bf16x8*)(Ab + row * 32 + j * 8);
            }
#pragma unroll
            for (int ni = 0; ni < 4; ni++) {
                int row = wn + ni * 16 + fr;
                int j = quad ^ ((row >> 1) & 3);
                bv[ni] = *(const bf16x8*)(Bb + row * 32 + j * 8);
            }
#pragma unroll
            for (int mi = 0; mi < 4; mi++) {
                acc[mi][0] = __builtin_amdgcn_mfma_f32_16x16x32_bf16(af[mi], bv[0], acc[mi][0], 0, 0, 0);
                acc[mi][1] = __builtin_amdgcn_mfma_f32_16x16x32_bf16(af[mi], bv[1], acc[mi][1], 0, 0, 0);
                acc[mi][2] = __builtin_amdgcn_mfma_f32_16x16x32_bf16(af[mi], bv[2], acc[mi][2], 0, 0, 0);
                acc[mi][3] = __builtin_amdgcn_mfma_f32_16x16x32_bf16(af[mi], bv[3], acc[mi][3], 0, 0, 0);
            }
            __syncthreads();
        }
#pragma unroll
        for (int ni = 0; ni < 4; ni++) {
            int n = n0 + wn + ni * 16 + fr;
            float bv = bias[n];
            int hh = (n >> 5) & 7, d = n & 31;
            if (n < 256) {                         // K: [b,h,s,d]
#pragma unroll
                for (int mi = 0; mi < 4; mi++) {
#pragma unroll
                    for (int r = 0; r < 4; r++) {
                        int m = m0 + wm + mi * 16 + quad * 4 + r;
                        int bb = m >> 12, s = m & (SS - 1);
                        Kb[((((size_t)bb * HH + hh) * SS + s) << 5) + d] =
                            f2bf(acc[mi][ni][r] + bv);
                    }
                }
            } else {                               // V: [b,h,d,s], 8B stores
#pragma unroll
                for (int mi = 0; mi < 4; mi++) {
                    int m = m0 + wm + mi * 16 + quad * 4;
                    int bb = m >> 12, s = m & (SS - 1);
                    union { unsigned short u[4]; uint2 v; } pk;
#pragma unroll
                    for (int r = 0; r < 4; r++)
                        pk.u[r] = f2bf(acc[mi][ni][r] + bv);
                    *(uint2*)&Vb[(((size_t)bb * HH + hh) * 32 + d) * SS + s] = pk.v;
                }
            }
        }
    } else if (bid < 1824) {
        int row = bid - 1024;
        unsigned* words = (unsigned*)smem;
        unsigned* orred = (unsigned*)(smem + 512);
        int w = t >> 6, lane = t & 63;
        const float* mp = mask + (size_t)row * SS + lane;
        float mv[16];
#pragma unroll
        for (int i = 0; i < 16; i++) mv[i] = mp[(w * 16 + i) * 64];
        unsigned lor = 0;
#pragma unroll
        for (int i = 0; i < 16; i++) {
            unsigned long long bal = __ballot(mv[i] > 0.f);
            if (lane == 0) {
                words[(w * 16 + i) * 2] = (unsigned)bal;
                words[(w * 16 + i) * 2 + 1] = (unsigned)(bal >> 32);
            }
            lor |= (unsigned)(bal | (bal >> 32));
        }
        if (lane == 0) orred[w] = lor;
        __syncthreads();
        unsigned anyv = orred[0] | orred[1] | orred[2] | orred[3];
        if (t < 128) Mbits[(size_t)row * 128 + t] = anyv ? words[t] : 0xFFFFFFFFu;
    } else {
        typedef unsigned short (*arow_t)[264];
        arow_t Aq = (arow_t)smem;
        float* mu_s = (float*)(smem + 16896);
        float* rs_s = mu_s + 32;
        float (*prt)[8][2] = (float(*)[8][2])(rs_s + 32);
        int idx = bid - 1824;
        int nq = idx & 1, my = idx >> 1;
        int m0 = my * 32;
        int row = t & 31, cs = t >> 5;
        const float* xp = queries + (size_t)(m0 + row) * DD + cs * 32;
        float s = 0.f, ss = 0.f;
#pragma unroll
        for (int c = 0; c < 32; c += 4) {
            float4 v = *(const float4*)(xp + c);
            s += v.x + v.y + v.z + v.w;
            ss += v.x * v.x + v.y * v.y + v.z * v.z + v.w * v.w;
        }
        prt[row][cs][0] = s; prt[row][cs][1] = ss;
        __syncthreads();
        if (t < 32) {
            float sum = 0.f, sq = 0.f;
#pragma unroll
            for (int k = 0; k < 8; k++) { sum += prt[t][k][0]; sq += prt[t][k][1]; }
            float mu = sum * (1.0f / DD);
            float var = sq * (1.0f / DD) - mu * mu;
            mu_s[t] = mu;
            rs_s[t] = rsqrtf(var + 1e-5f);
        }
        __syncthreads();
        {
            float mu = mu_s[row], r = rs_s[row];
            int col0 = cs * 32;
#pragma unroll
            for (int c = 0; c < 32; c += 8) {
                int col = col0 + c;
                float4 v0 = *(const float4*)(xp + c);
                float4 v1 = *(const float4*)(xp + c + 4);
                float4 g0 = *(const float4*)(ln_g + col);
                float4 g1 = *(const float4*)(ln_g + col + 4);
                float4 b0 = *(const float4*)(ln_b + col);
                float4 b1 = *(const float4*)(ln_b + col + 4);
                uint4 pk;
                pk.x = pkbf((v0.x - mu) * r * g0.x + b0.x, (v0.y - mu) * r * g0.y + b0.y);
                pk.y = pkbf((v0.z - mu) * r * g0.z + b0.z, (v0.w - mu) * r * g0.w + b0.w);
                pk.z = pkbf((v1.x - mu) * r * g1.x + b1.x, (v1.y - mu) * r * g1.y + b1.y);
                pk.w = pkbf((v1.z - mu) * r * g1.z + b1.z, (v1.w - mu) * r * g1.w + b1.w);
                *(uint4*)&Aq[row][col] = pk;
            }
        }
        __syncthreads();
        int w = t >> 6, lane = t & 63;
        int fr = lane & 15, quad = lane >> 4;
        int n0 = nq * 128 + w * 32;
        f32x4 acc[2][2] = {};
        const unsigned short* Wq0 = wbf + (size_t)(n0 + fr) * DD + quad * 8;
        const unsigned short* Wq1 = Wq0 + (size_t)16 * DD;
#pragma unroll
        for (int k0 = 0; k0 < DD; k0 += 32) {
            bf16x8 a0 = *(const bf16x8*)&Aq[fr][k0 + quad * 8];
            bf16x8 a1 = *(const bf16x8*)&Aq[16 + fr][k0 + quad * 8];
            bf16x8 w0 = *(const bf16x8*)(Wq0 + k0);
            bf16x8 w1 = *(const bf16x8*)(Wq1 + k0);
            acc[0][0] = __builtin_amdgcn_mfma_f32_16x16x32_bf16(a0, w0, acc[0][0], 0, 0, 0);
            acc[0][1] = __builtin_amdgcn_mfma_f32_16x16x32_bf16(a0, w1, acc[0][1], 0, 0, 0);
            acc[1][0] = __builtin_amdgcn_mfma_f32_16x16x32_bf16(a1, w0, acc[1][0], 0, 0, 0);
            acc[1][1] = __builtin_amdgcn_mfma_f32_16x16x32_bf16(a1, w1, acc[1][1], 0, 0, 0);
        }
#pragma unroll
        for (int ni = 0; ni < 2; ni++) {
            int n = n0 + ni * 16 + fr;
            float bv = cb[n];
#pragma unroll
            for (int mi = 0; mi < 2; mi++) {
#pragma unroll
                for (int r = 0; r < 4; r++) {
                    int m = m0 + mi * 16 + quad * 4 + r;
                    q_cross[(size_t)m * DD + n] =
                        f2bf((acc[mi][ni][r] + bv) * QSCALE);
                }
            }
        }
    }
}

// ---------------- fused LayerNorm + one-wave MFMA GEMM ----------------------
// MODE 1: bf16 out, GELU. MODE 3: bf16 out, Q-scale folded on cols < 256.
template<int MODE>
__global__ __launch_bounds__(64, 4) void ln_gemm(
        const float* __restrict__ X, const float* __restrict__ gam,
        const float* __restrict__ bet,
        const unsigned short* __restrict__ W, const float* __restrict__ bias,
        const float* __restrict__ res,
        float* __restrict__ C, unsigned short* __restrict__ Cb, int N) {
    __shared__ unsigned short As[32][264];
    __shared__ float mu_s[32], rs_s[32];
    __shared__ float prt[32][2][2];
    const int t = threadIdx.x;
    const int fr = t & 15, quad = t >> 4;
    const int m0 = blockIdx.y * 32, n0 = blockIdx.x * 32;
    const int row = t & 31, half = t >> 5;

    const float* xp = X + (size_t)(m0 + row) * DD + half * 128;
    float s = 0.f, ss = 0.f;
#pragma unroll
    for (int c = 0; c < 128; c += 4) {
        float4 v = *(const float4*)(xp + c);
        s += v.x + v.y + v.z + v.w;
        ss += v.x * v.x + v.y * v.y + v.z * v.z + v.w * v.w;
    }
    prt[row][half][0] = s;
    prt[row][half][1] = ss;
    __syncthreads();
    if (t < 32) {
        float sum = prt[t][0][0] + prt[t][1][0];
        float sq  = prt[t][0][1] + prt[t][1][1];
        float mu = sum * (1.0f / DD);
        float var = sq * (1.0f / DD) - mu * mu;
        mu_s[t] = mu;
        rs_s[t] = rsqrtf(var + 1e-5f);
    }
    __syncthreads();
    {
        float mu = mu_s[row], r = rs_s[row];
#pragma unroll
        for (int c = 0; c < 128; c += 8) {
            int col = half * 128 + c;
            float4 v0 = *(const float4*)(xp + c);
            float4 v1 = *(const float4*)(xp + c + 4);
            float4 g0 = *(const float4*)(gam + col);
            float4 g1 = *(const float4*)(gam + col + 4);
            float4 b0 = *(const float4*)(bet + col);
            float4 b1 = *(const float4*)(bet + col + 4);
            uint4 pk;
            pk.x = pkbf((v0.x - mu) * r * g0.x + b0.x, (v0.y - mu) * r * g0.y + b0.y);
            pk.y = pkbf((v0.z - mu) * r * g0.z + b0.z, (v0.w - mu) * r * g0.w + b0.w);
            pk.z = pkbf((v1.x - mu) * r * g1.x + b1.x, (v1.y - mu) * r * g1.y + b1.y);
            pk.w = pkbf((v1.z - mu) * r * g1.z + b1.z, (v1.w - mu) * r * g1.w + b1.w);
            *(uint4*)&As[row][col] = pk;
        }
    }
    __syncthreads();

    f32x4 acc[2][2] = {};
    const unsigned short* Wp0 = W + (size_t)(n0 + fr) * DD + quad * 8;
    const unsigned short* Wp1 = Wp0 + (size_t)16 * DD;
#pragma unroll
    for (int k0 = 0; k0 < DD; k0 += 32) {
        bf16x8 a0 = *(const bf16x8*)&As[fr][k0 + quad * 8];
        bf16x8 a1 = *(const bf16x8*)&As[16 + fr][k0 + quad * 8];
        bf16x8 w0 = *(const bf16x8*)(Wp0 + k0);
        bf16x8 w1 = *(const bf16x8*)(Wp1 + k0);
        acc[0][0] = __builtin_amdgcn_mfma_f32_16x16x32_bf16(a0, w0, acc[0][0], 0, 0, 0);
        acc[0][1] = __builtin_amdgcn_mfma_f32_16x16x32_bf16(a0, w1, acc[0][1], 0, 0, 0);
        acc[1][0] = __builtin_amdgcn_mfma_f32_16x16x32_bf16(a1, w0, acc[1][0], 0, 0, 0);
        acc[1][1] = __builtin_amdgcn_mfma_f32_16x16x32_bf16(a1, w1, acc[1][1], 0, 0, 0);
    }

#pragma unroll
    for (int ni = 0; ni < 2; ni++) {
        int n = n0 + ni * 16 + fr;
        float bv = bias[n];
#pragma unroll
        for (int mi = 0; mi < 2; mi++) {
#pragma unroll
            for (int r = 0; r < 4; r++) {
                int m = m0 + mi * 16 + quad * 4 + r;
                float v = acc[mi][ni][r] + bv;
                if (MODE == 1) {
                    v = 0.5f * v * (1.0f + erff(v * 0.70710678118654752f));
                    Cb[(size_t)m * N + n] = f2bf(v);
                } else if (MODE == 2) {
                    v += res[(size_t)m * N + n];
                    C[(size_t)m * N + n] = v;
                } else if (MODE == 3) {
                    if (n < 256) v *= QSCALE;
                    Cb[(size_t)m * N + n] = f2bf(v);
                } else {
                    C[(size_t)m * N + n] = v;
                }
            }
        }
    }
}

// ---------------- fused split-S combine + output projection -----------------
__global__ __launch_bounds__(64, 4) void comb_gemm(
        const float* __restrict__ Opart, const float* __restrict__ mpart,
        const float* __restrict__ lpart,
        const unsigned short* __restrict__ W, const float* __restrict__ bias,
        const float* __restrict__ res,
        float* __restrict__ C) {
    __shared__ unsigned short As[32][264];
    const int t = threadIdx.x;
    const int fr = t & 15, quad = t >> 4;
    const int m0 = blockIdx.y * 32, n0 = blockIdx.x * 32;
    const int row = t & 31, half = t >> 5;

    {
        int m = m0 + row;
        int b = m / BQ, q = m % BQ;
#pragma unroll
        for (int h = half * 4; h < half * 4 + 4; h++) {
            float mv[NSPLIT], wsp[NSPLIT];
            float mstar = -1e30f;
#pragma unroll
            for (int sp = 0; sp < NSPLIT; sp++) {
                mv[sp] = mpart[((size_t)(b * NSPLIT + sp) * HH + h) * BQ + q];
                mstar = fmaxf(mstar, mv[sp]);
            }
            float lstar = 0.f;
#pragma unroll
            for (int sp = 0; sp < NSPLIT; sp++) {
                wsp[sp] = __expf(mv[sp] - mstar);
                lstar += lpart[((size_t)(b * NSPLIT + sp) * HH + h) * BQ + q] * wsp[sp];
            }
            float inv = 1.0f / lstar;
#pragma unroll
            for (int d = 0; d < HDD; d += 8) {
                float o[8] = {};
#pragma unroll
                for (int sp = 0; sp < NSPLIT; sp++) {
                    const float* op = Opart +
                        ((size_t)(b * NSPLIT + sp) * BQ + q) * DD + h * HDD + d;
                    float4 a = *(const float4*)op;
                    float4 b4 = *(const float4*)(op + 4);
                    o[0] += a.x * wsp[sp];  o[1] += a.y * wsp[sp];
                    o[2] += a.z * wsp[sp];  o[3] += a.w * wsp[sp];
                    o[4] += b4.x * wsp[sp]; o[5] += b4.y * wsp[sp];
                    o[6] += b4.z * wsp[sp]; o[7] += b4.w * wsp[sp];
                }
                uint4 pk;
                pk.x = pkbf(o[0] * inv, o[1] * inv);
                pk.y = pkbf(o[2] * inv, o[3] * inv);
                pk.z = pkbf(o[4] * inv, o[5] * inv);
                pk.w = pkbf(o[6] * inv, o[7] * inv);
                *(uint4*)&As[row][h * HDD + d] = pk;
            }
        }
    }
    __syncthreads();

    f32x4 acc[2][2] = {};
    const unsigned short* Wp0 = W + (size_t)(n0 + fr) * DD + quad * 8;
    const unsigned short* Wp1 = Wp0 + (size_t)16 * DD;
#pragma unroll
    for (int k0 = 0; k0 < DD; k0 += 32) {
        bf16x8 a0 = *(const bf16x8*)&As[fr][k0 + quad * 8];
        bf16x8 a1 = *(const bf16x8*)&As[16 + fr][k0 + quad * 8];
        bf16x8 w0 = *(const bf16x8*)(Wp0 + k0);
        bf16x8 w1 = *(const bf16x8*)(Wp1 + k0);
        acc[0][0] = __builtin_amdgcn_mfma_f32_16x16x32_bf16(a0, w0, acc[0][0], 0, 0, 0);
        acc[0][1] = __builtin_amdgcn_mfma_f32_16x16x32_bf16(a0, w1, acc[0][1], 0, 0, 0);
        acc[1][0] = __builtin_amdgcn_mfma_f32_16x16x32_bf16(a1, w0, acc[1][0], 0, 0, 0);
        acc[1][1] = __builtin_amdgcn_mfma_f32_16x16x32_bf16(a1, w1, acc[1][1], 0, 0, 0);
    }

#pragma unroll
    for (int ni = 0; ni < 2; ni++) {
        int n = n0 + ni * 16 + fr;
        float bv = bias[n];
#pragma unroll
        for (int mi = 0; mi < 2; mi++) {
#pragma unroll
            for (int r = 0; r < 4; r++) {
                int m = m0 + mi * 16 + quad * 4 + r;
                float v = acc[mi][ni][r] + bv + res[(size_t)m * DD + n];
                C[(size_t)m * DD + n] = v;
            }
        }
    }
}

// ---------------- one-wave MFMA GEMM: bf16 A, 32x32 tile (SPLITK=1 only) ----
template<int KK, int MODE>
__global__ __launch_bounds__(64, 4) void gemm_skinny2(
        const unsigned short* __restrict__ A, const unsigned short* __restrict__ W,
        const float* __restrict__ bias, const float* __restrict__ res,
        float* __restrict__ C, int N) {
    const int lane = threadIdx.x;
    const int fr = lane & 15, quad = lane >> 4;
    const int m0 = blockIdx.y * 32;
    const int n0 = blockIdx.x * 32;

    f32x4 acc[2][2] = {};
    const unsigned short* Ap0 = A + (size_t)(m0 + fr) * KK + quad * 8;
    const unsigned short* Ap1 = Ap0 + (size_t)16 * KK;
    const unsigned short* Wp0 = W + (size_t)(n0 + fr) * KK + quad * 8;
    const unsigned short* Wp1 = Wp0 + (size_t)16 * KK;

#pragma unroll
    for (int k0 = 0; k0 < KK; k0 += 32) {
        bf16x8 a0 = *(const bf16x8*)(Ap0 + k0);
        bf16x8 a1 = *(const bf16x8*)(Ap1 + k0);
        bf16x8 w0 = *(const bf16x8*)(Wp0 + k0);
        bf16x8 w1 = *(const bf16x8*)(Wp1 + k0);
        acc[0][0] = __builtin_amdgcn_mfma_f32_16x16x32_bf16(a0, w0, acc[0][0], 0, 0, 0);
        acc[0][1] = __builtin_amdgcn_mfma_f32_16x16x32_bf16(a0, w1, acc[0][1], 0, 0, 0);
        acc[1][0] = __builtin_amdgcn_mfma_f32_16x16x32_bf16(a1, w0, acc[1][0], 0, 0, 0);
        acc[1][1] = __builtin_amdgcn_mfma_f32_16x16x32_bf16(a1, w1, acc[1][1], 0, 0, 0);
    }

#pragma unroll
    for (int ni = 0; ni < 2; ni++) {
        int n = n0 + ni * 16 + fr;
        float bv = bias[n];
#pragma unroll
        for (int mi = 0; mi < 2; mi++) {
#pragma unroll
            for (int r = 0; r < 4; r++) {
                int m = m0 + mi * 16 + quad * 4 + r;
                float v = acc[mi][ni][r] + bv;
                if (MODE == 1) {
                    v = 0.5f * v * (1.0f + erff(v * 0.70710678118654752f));
                } else if (MODE == 2) {
                    v += res[(size_t)m * N + n];
                }
                C[(size_t)m * N + n] = v;
            }
        }
    }
}

// ---------------- FFN2: K=1024 split across 4 waves, LDS reduce, fused ------
__global__ __launch_bounds__(256) void ffn2_gemm(
        const unsigned short* __restrict__ Hbf,
        const unsigned short* __restrict__ W2, const float* __restrict__ b2,
        const float* __restrict__ res, float* __restrict__ out) {
    __shared__ float part[3][32][33];
    const int t = threadIdx.x;
    const int w = t >> 6, lane = t & 63;
    const int fr = lane & 15, quad = lane >> 4;
    const int m0 = blockIdx.y * 32, n0 = blockIdx.x * 32;

    f32x4 acc[2][2] = {};
    const unsigned short* Ap0 = Hbf + (size_t)(m0 + fr) * 1024 + w * 256 + quad * 8;
    const unsigned short* Ap1 = Ap0 + (size_t)16 * 1024;
    const unsigned short* Wp0 = W2 + (size_t)(n0 + fr) * 1024 + w * 256 + quad * 8;
    const unsigned short* Wp1 = Wp0 + (size_t)16 * 1024;
#pragma unroll
    for (int k0 = 0; k0 < 256; k0 += 32) {
        bf16x8 a0 = *(const bf16x8*)(Ap0 + k0);
        bf16x8 a1 = *(const bf16x8*)(Ap1 + k0);
        bf16x8 w0 = *(const bf16x8*)(Wp0 + k0);
        bf16x8 w1 = *(const bf16x8*)(Wp1 + k0);
        acc[0][0] = __builtin_amdgcn_mfma_f32_16x16x32_bf16(a0, w0, acc[0][0], 0, 0, 0);
        acc[0][1] = __builtin_amdgcn_mfma_f32_16x16x32_bf16(a0, w1, acc[0][1], 0, 0, 0);
        acc[1][0] = __builtin_amdgcn_mfma_f32_16x16x32_bf16(a1, w0, acc[1][0], 0, 0, 0);
        acc[1][1] = __builtin_amdgcn_mfma_f32_16x16x32_bf16(a1, w1, acc[1][1], 0, 0, 0);
    }

    if (w > 0) {
#pragma unroll
        for (int ni = 0; ni < 2; ni++)
#pragma unroll
            for (int mi = 0; mi < 2; mi++)
#pragma unroll
                for (int r = 0; r < 4; r++)
                    part[w - 1][mi * 16 + quad * 4 + r][ni * 16 + fr] = acc[mi][ni][r];
    }
    __syncthreads();
    if (w == 0) {
#pragma unroll
        for (int ni = 0; ni < 2; ni++) {
            int n = n0 + ni * 16 + fr;
            float bv = b2[n];
#pragma unroll
            for (int mi = 0; mi < 2; mi++) {
#pragma unroll
                for (int r = 0; r < 4; r++) {
                    int row = mi * 16 + quad * 4 + r;
                    int m = m0 + row;
                    int col = ni * 16 + fr;
                    float v = acc[mi][ni][r] + part[0][row][col] +
                              part[1][row][col] + part[2][row][col] +
                              bv + res[(size_t)m * DD + n];
                    out[(size_t)m * DD + n] = v;
                }
            }
        }
    }
}

// ---------------- MFMA flash cross-attention, XCD-pair-swizzled grid --------
// 1D grid of 512; decode so the two qb blocks sharing one (b,h,sp) K/V chunk
// get the same wgid%8 -> same XCD -> second reader hits that XCD's L2.
// id = xcd + 16*k + 8*qb:  h = id&7, qb = (id>>3)&1, z = id>>4.
#define QT 64
#define ST 128

__global__ __launch_bounds__(256) void cross_attn_mfma(
        const unsigned short* __restrict__ Qm,
        const unsigned short* __restrict__ Kb,
        const unsigned short* __restrict__ Vb,
        const unsigned* __restrict__ Mbits,
        float* __restrict__ Opart,
        float* __restrict__ mpart,
        float* __restrict__ lpart) {
    __shared__ unsigned short Qs[QT][40];
    __shared__ unsigned short Ks[ST][40];
    __shared__ unsigned short Vt[HDD][136];
    __shared__ unsigned short Ps[QT][136];
    __shared__ unsigned Mq[QT][4];
    __shared__ float4 redm[QT];
    __shared__ float4 reds[QT];
    __shared__ float m_s[QT], alpha_s[QT], l_s[QT];

    const int id = blockIdx.x;
    const int h = id & 7;
    const int qb = (id >> 3) & 1;
    const int z = id >> 4;                 // 0..31
    const int b = z / NSPLIT, sp = z % NSPLIT;
    const int t = threadIdx.x;
    const int w = t >> 6, lane = t & 63;
    const int fr = lane & 15, quad = lane >> 4;
    const int q0 = qb * QT;
    const int qlim = min(BQ - q0, QT);

    {
        int q = t >> 2, c0 = (t & 3) * 8;
        uint4 pq = {0, 0, 0, 0};
        if (q < qlim)
            pq = *(const uint4*)(Qm + (size_t)(b * BQ + q0 + q) * DD + h * HDD + c0);
        *(uint4*)&Qs[q][c0] = pq;
        if (t < QT) { m_s[t] = -1e30f; l_s[t] = 0.f; }
    }

    f32x4 oacc[2] = {};
    const unsigned short* Kbase = Kb + (((size_t)(b * HH + h)) * SS << 5);
    const unsigned short* Vbase = Vb + (((size_t)(b * HH + h)) << 5) * SS;

    for (int s0 = sp * SCHUNK; s0 < (sp + 1) * SCHUNK; s0 += ST) {
        __syncthreads();                               // B1
        {
            int r = t >> 1, half = t & 1;
            const unsigned short* kp = Kbase + ((size_t)(s0 + r) << 5) + half * 16;
            *(uint4*)&Ks[r][half * 16] = *(const uint4*)kp;
            *(uint4*)&Ks[r][half * 16 + 8] = *(const uint4*)(kp + 8);
            int d = t >> 3, c = (t & 7) * 16;
            const unsigned short* vp = Vbase + (size_t)d * SS + s0 + c;
            *(uint4*)&Vt[d][c] = *(const uint4*)vp;
            *(uint4*)&Vt[d][c + 8] = *(const uint4*)(vp + 8);
        }
        {
            int q = t >> 2, wd = t & 3;
            unsigned mword = 0xFFFFFFFFu;
            if (q < qlim)
                mword = Mbits[(size_t)(b * BQ + q0 + q) * 128 + (s0 >> 5) + wd];
            Mq[q][wd] = mword;
        }
        __syncthreads();                               // B2

        bf16x8 af[2];
#pragma unroll
        for (int mt = 0; mt < 2; mt++)
            af[mt] = *(const bf16x8*)&Ks[w * 32 + mt * 16 + fr][quad * 8];
        f32x4 st[2][4];
#pragma unroll
        for (int nt = 0; nt < 4; nt++) {
            bf16x8 bq = *(const bf16x8*)&Qs[nt * 16 + fr][quad * 8];
#pragma unroll
            for (int mt = 0; mt < 2; mt++) {
                f32x4 z4 = {0.f, 0.f, 0.f, 0.f};
                st[mt][nt] = __builtin_amdgcn_mfma_f32_16x16x32_bf16(af[mt], bq, z4, 0, 0, 0);
            }
        }

        float mo[4];
#pragma unroll
        for (int nt = 0; nt < 4; nt++) mo[nt] = m_s[nt * 16 + fr];

        float pmax[4];
#pragma unroll
        for (int nt = 0; nt < 4; nt++) {
            unsigned mword = Mq[nt * 16 + fr][w];
            pmax[nt] = -1e30f;
#pragma unroll
            for (int mt = 0; mt < 2; mt++)
#pragma unroll
                for (int r = 0; r < 4; r++) {
                    int bitpos = mt * 16 + quad * 4 + r;
                    float v = st[mt][nt][r];
                    if (!((mword >> bitpos) & 1u)) v -= 10000.f;
                    st[mt][nt][r] = v;
                    pmax[nt] = fmaxf(pmax[nt], v);
                }
        }
#pragma unroll
        for (int nt = 0; nt < 4; nt++) {
            pmax[nt] = fmaxf(pmax[nt], __shfl_xor(pmax[nt], 16));
            pmax[nt] = fmaxf(pmax[nt], __shfl_xor(pmax[nt], 32));
        }
        if (quad == 0) {
#pragma unroll
            for (int nt = 0; nt < 4; nt++)
                ((float*)&redm[nt * 16 + fr])[w] = pmax[nt];
        }
        __syncthreads();                               // B3

        float mn[4], al[4];
#pragma unroll
        for (int nt = 0; nt < 4; nt++) {
            float4 rr = redm[nt * 16 + fr];
            float mt4 = fmaxf(fmaxf(rr.x, rr.y), fmaxf(rr.z, rr.w));
            mn[nt] = fmaxf(mo[nt], mt4);
            al[nt] = __expf(mo[nt] - mn[nt]);
        }
        if (w == 0 && quad == 0) {
#pragma unroll
            for (int nt = 0; nt < 4; nt++) {
                m_s[nt * 16 + fr] = mn[nt];
                alpha_s[nt * 16 + fr] = al[nt];
            }
        }

        float psum[4];
#pragma unroll
        for (int nt = 0; nt < 4; nt++) {
            psum[nt] = 0.f;
#pragma unroll
            for (int mt = 0; mt < 2; mt++) {
                float p0 = __expf(st[mt][nt][0] - mn[nt]);
                float p1 = __expf(st[mt][nt][1] - mn[nt]);
                float p2 = __expf(st[mt][nt][2] - mn[nt]);
                float p3 = __expf(st[mt][nt][3] - mn[nt]);
                psum[nt] += p0 + p1 + p2 + p3;
                uint2 pk;
                pk.x = pkbf(p0, p1);
                pk.y = pkbf(p2, p3);
                *(uint2*)&Ps[nt * 16 + fr][w * 32 + mt * 16 + quad * 4] = pk;
            }
        }
#pragma unroll
        for (int nt = 0; nt < 4; nt++) {
            psum[nt] += __shfl_xor(psum[nt], 16);
            psum[nt] += __shfl_xor(psum[nt], 32);
        }
        if (quad == 0) {
#pragma unroll
            for (int nt = 0; nt < 4; nt++)
                ((float*)&reds[nt * 16 + fr])[w] = psum[nt];
        }
        __syncthreads();                               // B4

        if (w == 0 && quad == 0) {
#pragma unroll
            for (int nt = 0; nt < 4; nt++) {
                int q = nt * 16 + fr;
                float4 ssum = reds[q];
                l_s[q] = l_s[q] * al[nt] + (ssum.x + ssum.y + ssum.z + ssum.w);
            }
        }

#pragma unroll
        for (int r = 0; r < 4; r++) {
            float a = alpha_s[w * 16 + quad * 4 + r];
            oacc[0][r] *= a; oacc[1][r] *= a;
        }
#pragma unroll
        for (int k0 = 0; k0 < ST; k0 += 32) {
            bf16x8 ap = *(const bf16x8*)&Ps[w * 16 + fr][k0 + quad * 8];
            bf16x8 bv0 = *(const bf16x8*)&Vt[fr][k0 + quad * 8];
            bf16x8 bv1 = *(const bf16x8*)&Vt[16 + fr][k0 + quad * 8];
            oacc[0] = __builtin_amdgcn_mfma_f32_16x16x32_bf16(ap, bv0, oacc[0], 0, 0, 0);
            oacc[1] = __builtin_amdgcn_mfma_f32_16x16x32_bf16(ap, bv1, oacc[1], 0, 0, 0);
        }
    }
    __syncthreads();

    int part = b * NSPLIT + sp;
    if (t < qlim) {
        mpart[((size_t)part * HH + h) * BQ + q0 + t] = m_s[t];
        lpart[((size_t)part * HH + h) * BQ + q0 + t] = l_s[t];
    }
#pragma unroll
    for (int nd = 0; nd < 2; nd++) {
#pragma unroll
        for (int r = 0; r < 4; r++) {
            int q = w * 16 + quad * 4 + r;
            if (q < qlim)
                Opart[((size_t)part * BQ + q0 + q) * DD + h * HDD + nd * 16 + fr] = oacc[nd][r];
        }
    }
}

// ---------------- self-attention (S=Q=100), MFMA single-pass ----------------
__global__ __launch_bounds__(256) void self_attn_mfma(
        const unsigned short* __restrict__ qkv, unsigned short* __restrict__ Out) {
    __shared__ unsigned short Qs[128][40];
    __shared__ unsigned short Vt[HDD][136];
    __shared__ unsigned short Ps[112][136];
    __shared__ float red[112][17];
    __shared__ float m_s[112], l_s[112];

    const int h = blockIdx.x, b = blockIdx.y;
    const int t = threadIdx.x;
    const int w = t >> 6, lane = t & 63;
    const int fr = lane & 15, quad = lane >> 4;

    {
        int r = t >> 1, half = t & 1;
        uint4 z = {0, 0, 0, 0};
        uint4 p0 = z, p1 = z, v0 = z, v1 = z;
        if (r < BQ) {
            const unsigned short* qp = qkv + (size_t)(b * BQ + r) * 768 + h * HDD + half * 16;
            p0 = *(const uint4*)qp;
            p1 = *(const uint4*)(qp + 8);
            const unsigned short* vp = qp + 512;
            v0 = *(const uint4*)vp;
            v1 = *(const uint4*)(vp + 8);
        }
        *(uint4*)&Qs[r][half * 16] = p0;
        *(uint4*)&Qs[r][half * 16 + 8] = p1;
        union { uint4 u; unsigned short s[8]; } a, c;
        a.u = v0; c.u = v1;
#pragma unroll
        for (int j = 0; j < 8; j++) Vt[half * 16 + j][r] = a.s[j];
#pragma unroll
        for (int j = 0; j < 8; j++) Vt[half * 16 + 8 + j][r] = c.s[j];
    }
    __syncthreads();

    bf16x8 af[2];
#pragma unroll
    for (int mt = 0; mt < 2; mt++) {
        int s = w * 32 + mt * 16 + fr;
        bf16x8 kz = {0, 0, 0, 0, 0, 0, 0, 0};
        af[mt] = kz;
        if (s < BQ)
            af[mt] = *(const bf16x8*)(qkv + (size_t)(b * BQ + s) * 768 + 256 + h * HDD + quad * 8);
    }
    f32x4 st[2][7];
#pragma unroll
    for (int nt = 0; nt < 7; nt++) {
        bf16x8 bq = *(const bf16x8*)&Qs[nt * 16 + fr][quad * 8];
#pragma unroll
        for (int mt = 0; mt < 2; mt++) {
            f32x4 z = {0.f, 0.f, 0.f, 0.f};
            st[mt][nt] = __builtin_amdgcn_mfma_f32_16x16x32_bf16(af[mt], bq, z, 0, 0, 0);
        }
    }

    float pmax[7];
#pragma unroll
    for (int nt = 0; nt < 7; nt++) {
        pmax[nt] = -1e30f;
#pragma unroll
        for (int mt = 0; mt < 2; mt++)
#pragma unroll
            for (int r = 0; r < 4; r++) {
                int s = w * 32 + mt * 16 + quad * 4 + r;
                float v = st[mt][nt][r];
                if (s >= BQ) v = -1e30f;
                st[mt][nt][r] = v;
                pmax[nt] = fmaxf(pmax[nt], v);
            }
        red[nt * 16 + fr][w * 4 + quad] = pmax[nt];
    }
    __syncthreads();
    if (t < 112) {
        float m = -1e30f;
#pragma unroll
        for (int k = 0; k < 16; k++) m = fmaxf(m, red[t][k]);
        m_s[t] = m;
    }
    __syncthreads();

    float psum[7];
#pragma unroll
    for (int nt = 0; nt < 7; nt++) {
        float mrow = m_s[nt * 16 + fr];
        psum[nt] = 0.f;
#pragma unroll
        for (int mt = 0; mt < 2; mt++) {
            float p0 = __expf(st[mt][nt][0] - mrow);
            float p1 = __expf(st[mt][nt][1] - mrow);
            float p2 = __expf(st[mt][nt][2] - mrow);
            float p3 = __expf(st[mt][nt][3] - mrow);
            psum[nt] += p0 + p1 + p2 + p3;
            uint2 pk;
            pk.x = pkbf(p0, p1);
            pk.y = pkbf(p2, p3);
            *(uint2*)&Ps[nt * 16 + fr][w * 32 + mt * 16 + quad * 4] = pk;
        }
        red[nt * 16 + fr][w * 4 + quad] = psum[nt];
    }
    __syncthreads();
    if (t < 112) {
        float s = 0.f;
#pragma unroll
        for (int k = 0; k < 16; k++) s += red[t][k];
        l_s[t] = s;
    }
    __syncthreads();

    f32x4 oacc[2][2] = {};
#pragma unroll
    for (int ti = 0; ti < 2; ti++) {
        int qt = w + ti * 4;
        if (qt < 7) {
#pragma unroll
            for (int k0 = 0; k0 < 128; k0 += 32) {
                bf16x8 ap = *(const bf16x8*)&Ps[qt * 16 + fr][k0 + quad * 8];
                bf16x8 bv0 = *(const bf16x8*)&Vt[fr][k0 + quad * 8];
                bf16x8 bv1 = *(const bf16x8*)&Vt[16 + fr][k0 + quad * 8];
                oacc[ti][0] = __builtin_amdgcn_mfma_f32_16x16x32_bf16(ap, bv0, oacc[ti][0], 0, 0, 0);
                oacc[ti][1] = __builtin_amdgcn_mfma_f32_16x16x32_bf16(ap, bv1, oacc[ti][1], 0, 0, 0);
            }
        }
    }
#pragma unroll
    for (int ti = 0; ti < 2; ti++) {
        int qt = w + ti * 4;
        if (qt < 7) {
#pragma unroll
            for (int nd = 0; nd < 2; nd++) {
#pragma unroll
                for (int r = 0; r < 4; r++) {
                    int q = qt * 16 + quad * 4 + r;
                    if (q < BQ) {
                        float inv = 1.0f / l_s[q];
                        Out[(size_t)(b * BQ + q) * DD + h * HDD + nd * 16 + fr] =
                            f2bf(oacc[ti][nd][r] * inv);
                    }
                }
            }
        }
    }
}

extern "C" void kernel_launch(void* const* d_in, const int* in_sizes, int n_in,
                              void* d_out, int out_size, void* d_ws, size_t ws_size,
                              hipStream_t stream) {
    const float* queries    = (const float*)d_in[0];
    const float* pixel_feat = (const float*)d_in[1];
    const float* prev_mask  = (const float*)d_in[2];
    const float* cross_in_w  = (const float*)d_in[3];
    const float* cross_in_b  = (const float*)d_in[4];
    const float* cross_out_w = (const float*)d_in[5];
    const float* cross_out_b = (const float*)d_in[6];
    const float* self_in_w   = (const float*)d_in[7];
    const float* self_in_b   = (const float*)d_in[8];
    const float* self_out_w  = (const float*)d_in[9];
    const float* self_out_b  = (const float*)d_in[10];
    const float* ln_cross_g  = (const float*)d_in[11];
    const float* ln_cross_b  = (const float*)d_in[12];
    const float* ln_self_g   = (const float*)d_in[13];
    const float* ln_self_b   = (const float*)d_in[14];
    const float* ln_ffn_g    = (const float*)d_in[15];
    const float* ln_ffn_b    = (const float*)d_in[16];
    const float* ffn_w1 = (const float*)d_in[17];
    const float* ffn_b1 = (const float*)d_in[18];
    const float* ffn_w2 = (const float*)d_in[19];
    const float* ffn_b2 = (const float*)d_in[20];
    float* out = (float*)d_out;

    const int NQ = SB * BQ;        // 800
    const int NK = SB * SS;        // 32768

    float* ws = (float*)d_ws;
    unsigned* Mbits = (unsigned*)ws;   ws += (size_t)NQ * 128;
    unsigned short* q_crossb = (unsigned short*)ws;  ws += (size_t)NQ * DD;  // bf16
    unsigned short* Kbk = (unsigned short*)ws;
    ws += (size_t)NK * DD / 2;
    unsigned short* Vbk = (unsigned short*)ws;
    ws += (size_t)NK * DD / 2;
    float* queries1 = ws;              ws += (size_t)NQ * DD;
    unsigned short* qkvb = (unsigned short*)ws;      ws += (size_t)NQ * 3 * DD;  // bf16
    unsigned short* attn2b = (unsigned short*)ws;    ws += (size_t)NQ * DD;      // bf16
    float* queries2 = ws;              ws += (size_t)NQ * DD;
    unsigned short* Hbf = (unsigned short*)ws;       ws += (size_t)NQ * 4 * DD;  // bf16
    float* Opart    = ws;              ws += (size_t)SB * NSPLIT * BQ * DD;
    float* mpart    = ws;              ws += (size_t)SB * NSPLIT * HH * BQ;
    float* lpart    = ws;              ws += (size_t)SB * NSPLIT * HH * BQ;
    unsigned short* wbf = (unsigned short*)ws;   // bf16 weights, WTOT shorts
    ws += WTOT / 2;
    unsigned short* Abf = (unsigned short*)ws;   // pixel_feat bf16

    // ---- weight + pixel_feat pre-conversion to bf16 ----
    wprep<<<4608, 256, 0, stream>>>(
        cross_in_w, self_in_w, cross_out_w, self_out_w, ffn_w1, ffn_w2,
        pixel_feat, wbf, Abf);

    // ---- stage1: KV proj + maskpack + LN/Q-proj (one dispatch) ----
    stage1<<<1874, 256, 0, stream>>>(
        queries, ln_cross_g, ln_cross_b, wbf, cross_in_b, q_crossb,
        Abf, Kbk, Vbk, prev_mask, Mbits);

    // ---- cross attention (XCD-pair-swizzled 1D grid) ----
    cross_attn_mfma<<<512, 256, 0, stream>>>(
        q_crossb, Kbk, Vbk, Mbits, Opart, mpart, lpart);
    comb_gemm<<<dim3(8, 25), 64, 0, stream>>>(
        Opart, mpart, lpart, wbf + WOFF_COW, cross_out_b, queries, queries1);

    // ---- self attention ----
    ln_gemm<3><<<dim3(24, 25), 64, 0, stream>>>(
        queries1, ln_self_g, ln_self_b, wbf + WOFF_SIW, self_in_b, nullptr,
        nullptr, qkvb, 3 * DD);
    self_attn_mfma<<<dim3(HH, SB), 256, 0, stream>>>(qkvb, attn2b);
    gemm_skinny2<256, 2><<<dim3(8, 25), 64, 0, stream>>>(
        attn2b, wbf + WOFF_SOW, self_out_b, queries1, queries2, DD);

    // ---- FFN ----
    ln_gemm<1><<<dim3(32, 25), 64, 0, stream>>>(
        queries2, ln_ffn_g, ln_ffn_b, wbf + WOFF_F1, ffn_b1, nullptr,
        nullptr, Hbf, 4 * DD);
    ffn2_gemm<<<dim3(8, 25), 256, 0, stream>>>(
        Hbf, wbf + WOFF_F2, ffn_b2, queries2, out);
}